// Round 1
// baseline (7367.979 us; speedup 1.0000x reference)
//
#include <hip/hip_runtime.h>
#include <hip/hip_bf16.h>

typedef short bf16x8 __attribute__((ext_vector_type(8)));
typedef unsigned short u16x8 __attribute__((ext_vector_type(8)));
typedef float f32x4 __attribute__((ext_vector_type(4)));

#define B_ 4
#define T_ 1024
#define V_ 1024
#define C_ 768
#define H_ 12
#define HS_ 64
#define L_ 6
#define F_ 3072
#define M_ (B_ * T_)   // 4096 rows

__device__ inline float b2f(unsigned short u) {
    return __uint_as_float(((unsigned int)u) << 16);
}

// ---------------- elementwise / embedding ----------------
__global__ void convert_bf16_kernel(const float* __restrict__ in,
                                    __hip_bfloat16* __restrict__ out, int n) {
    int i = blockIdx.x * 256 + threadIdx.x;
    if (i < n) out[i] = __float2bfloat16(in[i]);
}

__global__ void embed_kernel(const int* __restrict__ idx,
                             const float* __restrict__ wte,
                             const float* __restrict__ wpe,
                             float* __restrict__ x) {
    int i = blockIdx.x * 256 + threadIdx.x;  // 0 .. M_*C_-1
    int row = i / C_;
    int c = i - row * C_;
    int t = row & (T_ - 1);
    x[i] = wte[(size_t)idx[row] * C_ + c] + wpe[(size_t)t * C_ + c];
}

// ---------------- layernorm (row of 768, block 256) ----------------
__global__ void ln_kernel(const float* __restrict__ x,
                          const float* __restrict__ w,
                          const float* __restrict__ b,
                          __hip_bfloat16* __restrict__ out) {
    int row = blockIdx.x, tid = threadIdx.x;
    const float* xr = x + (size_t)row * C_;
    float v0 = xr[tid], v1 = xr[tid + 256], v2 = xr[tid + 512];
    __shared__ float red[256];
    red[tid] = v0 + v1 + v2;
    __syncthreads();
    for (int s = 128; s; s >>= 1) {
        if (tid < s) red[tid] += red[tid + s];
        __syncthreads();
    }
    float mean = red[0] * (1.0f / C_);
    __syncthreads();
    float d0 = v0 - mean, d1 = v1 - mean, d2 = v2 - mean;
    red[tid] = d0 * d0 + d1 * d1 + d2 * d2;
    __syncthreads();
    for (int s = 128; s; s >>= 1) {
        if (tid < s) red[tid] += red[tid + s];
        __syncthreads();
    }
    float rstd = rsqrtf(red[0] * (1.0f / C_) + 1e-5f);
    __hip_bfloat16* o = out + (size_t)row * C_;
    o[tid]       = __float2bfloat16(d0 * rstd * w[tid]       + b[tid]);
    o[tid + 256] = __float2bfloat16(d1 * rstd * w[tid + 256] + b[tid + 256]);
    o[tid + 512] = __float2bfloat16(d2 * rstd * w[tid + 512] + b[tid + 512]);
}

// ---------------- transpose-convert W[K][N] f32 -> WT[N][K] bf16 ----------------
__global__ void transpose_bf16_kernel(const float* __restrict__ W,
                                      __hip_bfloat16* __restrict__ WT,
                                      int K, int N) {
    __shared__ float tile[32][33];
    int n0 = blockIdx.x * 32, k0 = blockIdx.y * 32;
    int tx = threadIdx.x, ty = threadIdx.y;  // 32 x 8
    #pragma unroll
    for (int i = 0; i < 4; i++)
        tile[ty + 8 * i][tx] = W[(size_t)(k0 + ty + 8 * i) * N + n0 + tx];
    __syncthreads();
    #pragma unroll
    for (int i = 0; i < 4; i++)
        WT[(size_t)(n0 + ty + 8 * i) * K + k0 + tx] =
            __float2bfloat16(tile[tx][ty + 8 * i]);
}

// ---------------- MFMA GEMM: C[M][N] = A[M][K] * W[K][N] (WT = W^T, [N][K]) ----
// one wave per 64x64 output tile
template <bool BIAS, bool RES, bool RELU, bool OUTF, bool OUTB>
__global__ void gemm64_kernel(const __hip_bfloat16* __restrict__ A,
                              const __hip_bfloat16* __restrict__ WT,
                              const float* __restrict__ bias,
                              const float* __restrict__ res,
                              float* __restrict__ outF,
                              __hip_bfloat16* __restrict__ outB,
                              int M, int N, int K) {
    int lane = threadIdx.x;
    int row0 = blockIdx.y * 64, col0 = blockIdx.x * 64;
    int lr = lane & 15;
    int lk = (lane >> 4) << 3;
    f32x4 acc[4][4] = {};
    const short* Ap = (const short*)A + (size_t)(row0 + lr) * K + lk;
    const short* Bp = (const short*)WT + (size_t)(col0 + lr) * K + lk;
    for (int k0 = 0; k0 < K; k0 += 32) {
        bf16x8 a[4], b[4];
        #pragma unroll
        for (int i = 0; i < 4; i++)
            a[i] = *(const bf16x8*)(Ap + (size_t)16 * i * K + k0);
        #pragma unroll
        for (int j = 0; j < 4; j++)
            b[j] = *(const bf16x8*)(Bp + (size_t)16 * j * K + k0);
        #pragma unroll
        for (int i = 0; i < 4; i++)
            #pragma unroll
            for (int j = 0; j < 4; j++)
                acc[i][j] = __builtin_amdgcn_mfma_f32_16x16x32_bf16(
                    a[i], b[j], acc[i][j], 0, 0, 0);
    }
    int rbase = (lane >> 4) * 4;
    #pragma unroll
    for (int i = 0; i < 4; i++) {
        #pragma unroll
        for (int j = 0; j < 4; j++) {
            int col = col0 + 16 * j + lr;
            float bv = BIAS ? bias[col] : 0.0f;
            #pragma unroll
            for (int r = 0; r < 4; r++) {
                int row = row0 + 16 * i + rbase + r;
                size_t off = (size_t)row * N + col;
                float v = acc[i][j][r] + bv;
                if (RES) v += res[off];
                if (RELU) v = fmaxf(v, 0.0f);
                if (OUTF) outF[off] = v;
                if (OUTB) outB[off] = __float2bfloat16(v);
            }
        }
    }
}

// ---------------- attention: one wave per (b, h, t) ----------------
__global__ void attn_kernel(const __hip_bfloat16* __restrict__ qb,
                            const __hip_bfloat16* __restrict__ kb,
                            const __hip_bfloat16* __restrict__ vb,
                            __hip_bfloat16* __restrict__ attb) {
    int gid = blockIdx.x;          // (b*H + h)*T + t
    int t = gid & (T_ - 1);
    int bh = gid >> 10;
    int h = bh % H_;
    int b = bh / H_;
    int lane = threadIdx.x;

    __shared__ float qs[HS_];
    __shared__ float sc[T_];

    size_t baseq = ((size_t)(b * T_ + t) * C_) + h * HS_;
    qs[lane] = b2f(((const unsigned short*)qb)[baseq + lane]);
    __syncthreads();

    // pass 1: scores + local max (lane j handles keys j, j+64, ...)
    float mx = -1e30f;
    for (int j = lane; j <= t; j += 64) {
        const u16x8* kr =
            (const u16x8*)((const unsigned short*)kb + (size_t)(b * T_ + j) * C_ + h * HS_);
        float s = 0.0f;
        #pragma unroll
        for (int c = 0; c < 8; c++) {
            u16x8 kv = kr[c];
            #pragma unroll
            for (int e = 0; e < 8; e++) s += qs[8 * c + e] * b2f(kv[e]);
        }
        s *= 0.125f;
        sc[j] = s;
        mx = fmaxf(mx, s);
    }
    #pragma unroll
    for (int o = 32; o; o >>= 1) mx = fmaxf(mx, __shfl_xor(mx, o));

    // pass 2: exp + sum
    float sum = 0.0f;
    for (int j = lane; j <= t; j += 64) {
        float p = __expf(sc[j] - mx);
        sc[j] = p;
        sum += p;
    }
    #pragma unroll
    for (int o = 32; o; o >>= 1) sum += __shfl_xor(sum, o);
    __syncthreads();

    // pass 3: lane = head dim d
    float inv = 1.0f / sum;
    float o = 0.0f;
    const unsigned short* vp = (const unsigned short*)vb + (size_t)b * T_ * C_ + h * HS_ + lane;
    for (int j = 0; j <= t; j++) {
        o += sc[j] * b2f(vp[(size_t)j * C_]);
    }
    attb[baseq + lane] = __float2bfloat16(o * inv);
}

// ---------------- loss ----------------
__global__ void loss_rows_kernel(const float* __restrict__ logits,
                                 const int* __restrict__ targets,
                                 float* __restrict__ partials) {
    int row = blockIdx.x, tid = threadIdx.x;
    const float* lr = logits + (size_t)row * V_;
    __shared__ float red[256];
    float mx = -1e30f;
    for (int i = tid; i < V_; i += 256) mx = fmaxf(mx, lr[i]);
    red[tid] = mx;
    __syncthreads();
    for (int s = 128; s; s >>= 1) {
        if (tid < s) red[tid] = fmaxf(red[tid], red[tid + s]);
        __syncthreads();
    }
    mx = red[0];
    __syncthreads();
    float sum = 0.0f;
    for (int i = tid; i < V_; i += 256) sum += __expf(lr[i] - mx);
    red[tid] = sum;
    __syncthreads();
    for (int s = 128; s; s >>= 1) {
        if (tid < s) red[tid] += red[tid + s];
        __syncthreads();
    }
    if (tid == 0) {
        float lse = mx + __logf(red[0]);
        partials[row] = lse - lr[targets[row]];
    }
}

__global__ void loss_reduce_kernel(const float* __restrict__ partials,
                                   float* __restrict__ out) {
    int tid = threadIdx.x;
    float s = 0.0f;
    for (int i = tid; i < M_; i += 256) s += partials[i];
    __shared__ float red[256];
    red[tid] = s;
    __syncthreads();
    for (int st = 128; st; st >>= 1) {
        if (tid < st) red[tid] += red[tid + st];
        __syncthreads();
    }
    if (tid == 0) out[0] = red[0] * (1.0f / M_);
}

// ---------------- launch ----------------
extern "C" void kernel_launch(void* const* d_in, const int* in_sizes, int n_in,
                              void* d_out, int out_size, void* d_ws, size_t ws_size,
                              hipStream_t stream) {
    const int*   idx     = (const int*)d_in[0];
    const int*   targets = (const int*)d_in[1];
    const float* wte     = (const float*)d_in[2];
    const float* wpe     = (const float*)d_in[3];
    const float* lm_b    = (const float*)d_in[4];
    const float* ln1_w   = (const float*)d_in[5];
    const float* ln1_b   = (const float*)d_in[6];
    const float* Wq      = (const float*)d_in[7];
    const float* Wk      = (const float*)d_in[8];
    const float* Wv      = (const float*)d_in[9];
    const float* projW   = (const float*)d_in[10];
    const float* projb   = (const float*)d_in[11];
    const float* ln2_w   = (const float*)d_in[12];
    const float* ln2_b   = (const float*)d_in[13];
    const float* fc1W    = (const float*)d_in[14];
    const float* fc1b    = (const float*)d_in[15];
    const float* fc2W    = (const float*)d_in[16];
    const float* fc2b    = (const float*)d_in[17];
    const float* lnfw    = (const float*)d_in[18];
    const float* lnfb    = (const float*)d_in[19];

    char* ws = (char*)d_ws;
    size_t off = 0;
    float* x = (float*)(ws + off);                 off += (size_t)M_ * C_ * 4;   // 12.6 MB
    __hip_bfloat16* h    = (__hip_bfloat16*)(ws + off); off += (size_t)M_ * C_ * 2;
    size_t qb_off = off;
    __hip_bfloat16* qb   = (__hip_bfloat16*)(ws + off); off += (size_t)M_ * C_ * 2;
    __hip_bfloat16* kb   = (__hip_bfloat16*)(ws + off); off += (size_t)M_ * C_ * 2;
    __hip_bfloat16* vb   = (__hip_bfloat16*)(ws + off); off += (size_t)M_ * C_ * 2;
    __hip_bfloat16* attb = (__hip_bfloat16*)(ws + off); off += (size_t)M_ * C_ * 2;
    __hip_bfloat16* fb   = (__hip_bfloat16*)(ws + qb_off);  // aliases qb..attb (dead then)
    __hip_bfloat16* wqT  = (__hip_bfloat16*)(ws + off); off += (size_t)C_ * C_ * 2;
    __hip_bfloat16* wkT  = (__hip_bfloat16*)(ws + off); off += (size_t)C_ * C_ * 2;
    __hip_bfloat16* wvT  = (__hip_bfloat16*)(ws + off); off += (size_t)C_ * C_ * 2;
    __hip_bfloat16* wpT  = (__hip_bfloat16*)(ws + off); off += (size_t)C_ * C_ * 2;
    __hip_bfloat16* wf1T = (__hip_bfloat16*)(ws + off); off += (size_t)C_ * F_ * 2;
    __hip_bfloat16* wf2T = (__hip_bfloat16*)(ws + off); off += (size_t)F_ * C_ * 2;
    __hip_bfloat16* wteB = (__hip_bfloat16*)(ws + off); off += (size_t)V_ * C_ * 2;
    float* partials = (float*)(ws + off);          off += (size_t)M_ * 4;

    float* logits = (float*)d_out;
    float* loss   = (float*)d_out + (size_t)M_ * V_;

    // wte -> bf16 (used as WT for the weight-tied lm head: WT[n][k] = wte[n][k])
    convert_bf16_kernel<<<(V_ * C_ + 255) / 256, 256, 0, stream>>>(wte, wteB, V_ * C_);
    // embedding
    embed_kernel<<<(M_ * C_) / 256, 256, 0, stream>>>(idx, wte, wpe, x);

    for (int l = 0; l < L_; l++) {
        ln_kernel<<<M_, 256, 0, stream>>>(x, ln1_w + l * C_, ln1_b + l * C_, h);

        transpose_bf16_kernel<<<dim3(C_ / 32, C_ / 32), dim3(32, 8), 0, stream>>>(
            Wq + (size_t)l * C_ * C_, wqT, C_, C_);
        transpose_bf16_kernel<<<dim3(C_ / 32, C_ / 32), dim3(32, 8), 0, stream>>>(
            Wk + (size_t)l * C_ * C_, wkT, C_, C_);
        transpose_bf16_kernel<<<dim3(C_ / 32, C_ / 32), dim3(32, 8), 0, stream>>>(
            Wv + (size_t)l * C_ * C_, wvT, C_, C_);

        gemm64_kernel<false, false, false, false, true><<<dim3(C_ / 64, M_ / 64), 64, 0, stream>>>(
            h, wqT, nullptr, nullptr, nullptr, qb, M_, C_, C_);
        gemm64_kernel<false, false, false, false, true><<<dim3(C_ / 64, M_ / 64), 64, 0, stream>>>(
            h, wkT, nullptr, nullptr, nullptr, kb, M_, C_, C_);
        gemm64_kernel<false, false, false, false, true><<<dim3(C_ / 64, M_ / 64), 64, 0, stream>>>(
            h, wvT, nullptr, nullptr, nullptr, vb, M_, C_, C_);

        attn_kernel<<<B_ * H_ * T_, 64, 0, stream>>>(qb, kb, vb, attb);

        transpose_bf16_kernel<<<dim3(C_ / 32, C_ / 32), dim3(32, 8), 0, stream>>>(
            projW + (size_t)l * C_ * C_, wpT, C_, C_);
        gemm64_kernel<true, true, false, true, false><<<dim3(C_ / 64, M_ / 64), 64, 0, stream>>>(
            attb, wpT, projb + l * C_, x, x, nullptr, M_, C_, C_);

        ln_kernel<<<M_, 256, 0, stream>>>(x, ln2_w + l * C_, ln2_b + l * C_, h);

        transpose_bf16_kernel<<<dim3(F_ / 32, C_ / 32), dim3(32, 8), 0, stream>>>(
            fc1W + (size_t)l * C_ * F_, wf1T, C_, F_);
        gemm64_kernel<true, false, true, false, true><<<dim3(F_ / 64, M_ / 64), 64, 0, stream>>>(
            h, wf1T, fc1b + l * F_, nullptr, nullptr, fb, M_, F_, C_);

        transpose_bf16_kernel<<<dim3(C_ / 32, F_ / 32), dim3(32, 8), 0, stream>>>(
            fc2W + (size_t)l * F_ * C_, wf2T, F_, C_);
        gemm64_kernel<true, true, false, true, false><<<dim3(C_ / 64, M_ / 64), 64, 0, stream>>>(
            fb, wf2T, fc2b + l * C_, x, x, nullptr, M_, C_, F_);
    }

    ln_kernel<<<M_, 256, 0, stream>>>(x, lnfw, lnfb, h);
    gemm64_kernel<true, false, false, true, false><<<dim3(V_ / 64, M_ / 64), 64, 0, stream>>>(
        h, wteB, lm_b, nullptr, logits, nullptr, M_, V_, C_);

    loss_rows_kernel<<<M_, 256, 0, stream>>>(logits, targets, partials);
    loss_reduce_kernel<<<1, 256, 0, stream>>>(partials, loss);
}

// Round 2
// 2495.362 us; speedup vs baseline: 2.9527x; 2.9527x over previous
//
#include <hip/hip_runtime.h>
#include <hip/hip_bf16.h>

typedef short bf16x8 __attribute__((ext_vector_type(8)));
typedef unsigned short u16x8 __attribute__((ext_vector_type(8)));
typedef float f32x4 __attribute__((ext_vector_type(4)));

#define B_ 4
#define T_ 1024
#define V_ 1024
#define C_ 768
#define H_ 12
#define HS_ 64
#define L_ 6
#define F_ 3072
#define M_ (B_ * T_)   // 4096 rows

__device__ inline float b2f(unsigned short u) {
    return __uint_as_float(((unsigned int)u) << 16);
}
__device__ inline unsigned short f2bbits(float f) {
    __hip_bfloat16 h = __float2bfloat16(f);
    return *(unsigned short*)&h;
}

// ---------------- elementwise / embedding ----------------
__global__ void convert_bf16_kernel(const float* __restrict__ in,
                                    __hip_bfloat16* __restrict__ out, int n) {
    int i = blockIdx.x * 256 + threadIdx.x;
    if (i < n) out[i] = __float2bfloat16(in[i]);
}

__global__ void embed_kernel(const int* __restrict__ idx,
                             const float* __restrict__ wte,
                             const float* __restrict__ wpe,
                             float* __restrict__ x) {
    int i = blockIdx.x * 256 + threadIdx.x;  // 0 .. M_*C_-1
    int row = i / C_;
    int c = i - row * C_;
    int t = row & (T_ - 1);
    x[i] = wte[(size_t)idx[row] * C_ + c] + wpe[(size_t)t * C_ + c];
}

// ---------------- layernorm (row of 768, block 256) ----------------
__global__ void ln_kernel(const float* __restrict__ x,
                          const float* __restrict__ w,
                          const float* __restrict__ b,
                          __hip_bfloat16* __restrict__ out) {
    int row = blockIdx.x, tid = threadIdx.x;
    const float* xr = x + (size_t)row * C_;
    float v0 = xr[tid], v1 = xr[tid + 256], v2 = xr[tid + 512];
    __shared__ float red[256];
    red[tid] = v0 + v1 + v2;
    __syncthreads();
    for (int s = 128; s; s >>= 1) {
        if (tid < s) red[tid] += red[tid + s];
        __syncthreads();
    }
    float mean = red[0] * (1.0f / C_);
    __syncthreads();
    float d0 = v0 - mean, d1 = v1 - mean, d2 = v2 - mean;
    red[tid] = d0 * d0 + d1 * d1 + d2 * d2;
    __syncthreads();
    for (int s = 128; s; s >>= 1) {
        if (tid < s) red[tid] += red[tid + s];
        __syncthreads();
    }
    float rstd = rsqrtf(red[0] * (1.0f / C_) + 1e-5f);
    __hip_bfloat16* o = out + (size_t)row * C_;
    o[tid]       = __float2bfloat16(d0 * rstd * w[tid]       + b[tid]);
    o[tid + 256] = __float2bfloat16(d1 * rstd * w[tid + 256] + b[tid + 256]);
    o[tid + 512] = __float2bfloat16(d2 * rstd * w[tid + 512] + b[tid + 512]);
}

// ---------------- transpose-convert W[K][N] f32 -> WT[N][K] bf16 ----------------
__global__ void transpose_bf16_kernel(const float* __restrict__ W,
                                      __hip_bfloat16* __restrict__ WT,
                                      int K, int N) {
    __shared__ float tile[32][33];
    int n0 = blockIdx.x * 32, k0 = blockIdx.y * 32;
    int tx = threadIdx.x, ty = threadIdx.y;  // 32 x 8
    #pragma unroll
    for (int i = 0; i < 4; i++)
        tile[ty + 8 * i][tx] = W[(size_t)(k0 + ty + 8 * i) * N + n0 + tx];
    __syncthreads();
    #pragma unroll
    for (int i = 0; i < 4; i++)
        WT[(size_t)(n0 + ty + 8 * i) * K + k0 + tx] =
            __float2bfloat16(tile[tx][ty + 8 * i]);
}

// ---------------- MFMA GEMM: C[M][N] = A[M][K] * W[K][N] (WT = W^T, [N][K]) ----
// one wave per 64x64 output tile
template <bool BIAS, bool RES, bool RELU, bool OUTF, bool OUTB>
__global__ void gemm64_kernel(const __hip_bfloat16* __restrict__ A,
                              const __hip_bfloat16* __restrict__ WT,
                              const float* __restrict__ bias,
                              const float* __restrict__ res,
                              float* __restrict__ outF,
                              __hip_bfloat16* __restrict__ outB,
                              int M, int N, int K) {
    int lane = threadIdx.x;
    int row0 = blockIdx.y * 64, col0 = blockIdx.x * 64;
    int lr = lane & 15;
    int lk = (lane >> 4) << 3;
    f32x4 acc[4][4] = {};
    const short* Ap = (const short*)A + (size_t)(row0 + lr) * K + lk;
    const short* Bp = (const short*)WT + (size_t)(col0 + lr) * K + lk;
    for (int k0 = 0; k0 < K; k0 += 32) {
        bf16x8 a[4], b[4];
        #pragma unroll
        for (int i = 0; i < 4; i++)
            a[i] = *(const bf16x8*)(Ap + (size_t)16 * i * K + k0);
        #pragma unroll
        for (int j = 0; j < 4; j++)
            b[j] = *(const bf16x8*)(Bp + (size_t)16 * j * K + k0);
        #pragma unroll
        for (int i = 0; i < 4; i++)
            #pragma unroll
            for (int j = 0; j < 4; j++)
                acc[i][j] = __builtin_amdgcn_mfma_f32_16x16x32_bf16(
                    a[i], b[j], acc[i][j], 0, 0, 0);
    }
    int rbase = (lane >> 4) * 4;
    #pragma unroll
    for (int i = 0; i < 4; i++) {
        #pragma unroll
        for (int j = 0; j < 4; j++) {
            int col = col0 + 16 * j + lr;
            float bv = BIAS ? bias[col] : 0.0f;
            #pragma unroll
            for (int r = 0; r < 4; r++) {
                int row = row0 + 16 * i + rbase + r;
                size_t off = (size_t)row * N + col;
                float v = acc[i][j][r] + bv;
                if (RES) v += res[off];
                if (RELU) v = fmaxf(v, 0.0f);
                if (OUTF) outF[off] = v;
                if (OUTB) outB[off] = __float2bfloat16(v);
            }
        }
    }
}

// ---------------- flash attention: block = (b, h, 64 q rows), 4 waves ----------
// wave w handles q rows qb0 + w*16 .. +15
__global__ __launch_bounds__(256) void attn_flash_kernel(
    const __hip_bfloat16* __restrict__ qb,
    const __hip_bfloat16* __restrict__ kb,
    const __hip_bfloat16* __restrict__ vb,
    __hip_bfloat16* __restrict__ attb) {
    int tid = threadIdx.x;
    int lane = tid & 63;
    int w = tid >> 6;               // wave 0..3
    int l15 = lane & 15;
    int l4 = lane >> 4;             // 0..3
    int qb0 = blockIdx.x * 64;
    int h = blockIdx.y;
    int b = blockIdx.z;

    __shared__ __align__(16) unsigned short Ks[64 * 64];      // swizzled [key][d]
    __shared__ __align__(16) unsigned short Vt[64 * 64];      // swizzled [d][key]
    __shared__ __align__(16) unsigned short Ps[4 * 16 * 64];  // per-wave [q][key]

    const unsigned short* Kg = (const unsigned short*)kb + (size_t)b * T_ * C_ + h * HS_;
    const unsigned short* Vg = (const unsigned short*)vb + (size_t)b * T_ * C_ + h * HS_;
    const unsigned short* Qg = (const unsigned short*)qb + (size_t)(b * T_ + qb0) * C_ + h * HS_;

    // Q fragments (A operand): lane holds Q[row=l15][d = kk*32 + l4*8 + e]
    bf16x8 qfrag[2];
    {
        const short* qrow = (const short*)Qg + (size_t)(w * 16 + l15) * C_;
        qfrag[0] = *(const bf16x8*)(qrow + l4 * 8);
        qfrag[1] = *(const bf16x8*)(qrow + 32 + l4 * 8);
    }

    f32x4 o_acc[4] = {};
    float m_run[4], l_run[4];
    #pragma unroll
    for (int r = 0; r < 4; r++) { m_run[r] = -1e30f; l_run[r] = 0.0f; }

    unsigned short* Pw = Ps + w * 16 * 64;
    int nkb = blockIdx.x + 1;

    for (int kbi = 0; kbi < nkb; ++kbi) {
        int k0 = kbi * 64;
        __syncthreads();
        // ---- stage K (swizzled) and V (transposed+swizzled) ----
        {
            int key = tid >> 3, ch = tid & 7;
            #pragma unroll
            for (int it = 0; it < 2; ++it) {
                int ky = key + it * 32;
                u16x8 kv = *(const u16x8*)(Kg + (size_t)(k0 + ky) * C_ + ch * 8);
                int byteoff = ky * 128 + ((ch * 16) ^ ((ky & 7) << 4));
                *(u16x8*)((char*)Ks + byteoff) = kv;

                u16x8 vv = *(const u16x8*)(Vg + (size_t)(k0 + ky) * C_ + ch * 8);
                #pragma unroll
                for (int e = 0; e < 8; ++e) {
                    int d = ch * 8 + e;
                    int slot = (d ^ (d >> 3)) & 7;
                    int boff = d * 128 + ((ky * 2) ^ (slot << 4));
                    *(unsigned short*)((char*)Vt + boff) = (unsigned short)vv[e];
                }
            }
        }
        __syncthreads();

        // ---- S = Q K^T ----
        f32x4 s[4] = {};
        #pragma unroll
        for (int kk = 0; kk < 2; ++kk) {
            #pragma unroll
            for (int nt = 0; nt < 4; ++nt) {
                int key = nt * 16 + l15;
                int boff = key * 128 + (((l4 * 16) + kk * 64) ^ ((key & 7) << 4));
                bf16x8 kf = *(const bf16x8*)((char*)Ks + boff);
                s[nt] = __builtin_amdgcn_mfma_f32_16x16x32_bf16(qfrag[kk], kf, s[nt], 0, 0, 0);
            }
        }

        // ---- scale + causal mask ----
        bool last = (kbi == nkb - 1);
        #pragma unroll
        for (int nt = 0; nt < 4; ++nt)
            #pragma unroll
            for (int r = 0; r < 4; ++r) {
                float v = s[nt][r] * 0.125f;
                if (last) {
                    int key = k0 + nt * 16 + l15;
                    int q = qb0 + w * 16 + l4 * 4 + r;
                    if (key > q) v = -1e30f;
                }
                s[nt][r] = v;
            }

        // ---- online softmax (per q-row r, 16-lane group reduce) ----
        #pragma unroll
        for (int r = 0; r < 4; ++r) {
            float mx = fmaxf(fmaxf(s[0][r], s[1][r]), fmaxf(s[2][r], s[3][r]));
            #pragma unroll
            for (int o = 8; o; o >>= 1) mx = fmaxf(mx, __shfl_xor(mx, o));
            float mnew = fmaxf(m_run[r], mx);
            float alpha = __expf(m_run[r] - mnew);
            m_run[r] = mnew;
            float rs = 0.0f;
            #pragma unroll
            for (int nt = 0; nt < 4; ++nt) {
                float p = __expf(s[nt][r] - mnew);
                s[nt][r] = p;
                rs += p;
            }
            #pragma unroll
            for (int o = 8; o; o >>= 1) rs += __shfl_xor(rs, o);
            l_run[r] = l_run[r] * alpha + rs;
            #pragma unroll
            for (int nt = 0; nt < 4; ++nt) o_acc[nt][r] *= alpha;
        }

        // ---- write P to per-wave LDS (C layout -> swizzled [q][key]) ----
        #pragma unroll
        for (int nt = 0; nt < 4; ++nt)
            #pragma unroll
            for (int r = 0; r < 4; ++r) {
                int q = l4 * 4 + r;
                int col = nt * 16 + l15;
                int slot = (q ^ (q >> 3)) & 7;
                int boff = q * 128 + ((col * 2) ^ (slot << 4));
                *(unsigned short*)((char*)Pw + boff) = f2bbits(s[nt][r]);
            }

        // ---- O += P V ----
        #pragma unroll
        for (int kk = 0; kk < 2; ++kk) {
            int q = l15;
            int pslot = (q ^ (q >> 3)) & 7;
            int pboff = q * 128 + (((l4 * 16) + kk * 64) ^ (pslot << 4));
            bf16x8 pf = *(const bf16x8*)((char*)Pw + pboff);
            #pragma unroll
            for (int nt = 0; nt < 4; ++nt) {
                int d = nt * 16 + l15;
                int dslot = (d ^ (d >> 3)) & 7;
                int vboff = d * 128 + (((l4 * 16) + kk * 64) ^ (dslot << 4));
                bf16x8 vf = *(const bf16x8*)((char*)Vt + vboff);
                o_acc[nt] = __builtin_amdgcn_mfma_f32_16x16x32_bf16(pf, vf, o_acc[nt], 0, 0, 0);
            }
        }
    }

    // ---- epilogue: O /= l, write bf16 ----
    unsigned short* Og = (unsigned short*)attb + (size_t)(b * T_ + qb0) * C_ + h * HS_;
    #pragma unroll
    for (int r = 0; r < 4; ++r) {
        float inv = 1.0f / l_run[r];
        #pragma unroll
        for (int nt = 0; nt < 4; ++nt) {
            float val = o_acc[nt][r] * inv;
            Og[(size_t)(w * 16 + l4 * 4 + r) * C_ + nt * 16 + l15] = f2bbits(val);
        }
    }
}

// ---------------- loss ----------------
__global__ void loss_rows_kernel(const float* __restrict__ logits,
                                 const int* __restrict__ targets,
                                 float* __restrict__ partials) {
    int row = blockIdx.x, tid = threadIdx.x;
    const float* lr = logits + (size_t)row * V_;
    __shared__ float red[256];
    float mx = -1e30f;
    for (int i = tid; i < V_; i += 256) mx = fmaxf(mx, lr[i]);
    red[tid] = mx;
    __syncthreads();
    for (int s = 128; s; s >>= 1) {
        if (tid < s) red[tid] = fmaxf(red[tid], red[tid + s]);
        __syncthreads();
    }
    mx = red[0];
    __syncthreads();
    float sum = 0.0f;
    for (int i = tid; i < V_; i += 256) sum += __expf(lr[i] - mx);
    red[tid] = sum;
    __syncthreads();
    for (int s = 128; s; s >>= 1) {
        if (tid < s) red[tid] += red[tid + s];
        __syncthreads();
    }
    if (tid == 0) {
        float lse = mx + __logf(red[0]);
        partials[row] = lse - lr[targets[row]];
    }
}

__global__ void loss_reduce_kernel(const float* __restrict__ partials,
                                   float* __restrict__ out) {
    int tid = threadIdx.x;
    float s = 0.0f;
    for (int i = tid; i < M_; i += 256) s += partials[i];
    __shared__ float red[256];
    red[tid] = s;
    __syncthreads();
    for (int st = 128; st; st >>= 1) {
        if (tid < st) red[tid] += red[tid + st];
        __syncthreads();
    }
    if (tid == 0) out[0] = red[0] * (1.0f / M_);
}

// ---------------- launch ----------------
extern "C" void kernel_launch(void* const* d_in, const int* in_sizes, int n_in,
                              void* d_out, int out_size, void* d_ws, size_t ws_size,
                              hipStream_t stream) {
    const int*   idx     = (const int*)d_in[0];
    const int*   targets = (const int*)d_in[1];
    const float* wte     = (const float*)d_in[2];
    const float* wpe     = (const float*)d_in[3];
    const float* lm_b    = (const float*)d_in[4];
    const float* ln1_w   = (const float*)d_in[5];
    const float* ln1_b   = (const float*)d_in[6];
    const float* Wq      = (const float*)d_in[7];
    const float* Wk      = (const float*)d_in[8];
    const float* Wv      = (const float*)d_in[9];
    const float* projW   = (const float*)d_in[10];
    const float* projb   = (const float*)d_in[11];
    const float* ln2_w   = (const float*)d_in[12];
    const float* ln2_b   = (const float*)d_in[13];
    const float* fc1W    = (const float*)d_in[14];
    const float* fc1b    = (const float*)d_in[15];
    const float* fc2W    = (const float*)d_in[16];
    const float* fc2b    = (const float*)d_in[17];
    const float* lnfw    = (const float*)d_in[18];
    const float* lnfb    = (const float*)d_in[19];

    char* ws = (char*)d_ws;
    size_t off = 0;
    float* x = (float*)(ws + off);                 off += (size_t)M_ * C_ * 4;
    __hip_bfloat16* h    = (__hip_bfloat16*)(ws + off); off += (size_t)M_ * C_ * 2;
    size_t qb_off = off;
    __hip_bfloat16* qb   = (__hip_bfloat16*)(ws + off); off += (size_t)M_ * C_ * 2;
    __hip_bfloat16* kb   = (__hip_bfloat16*)(ws + off); off += (size_t)M_ * C_ * 2;
    __hip_bfloat16* vb   = (__hip_bfloat16*)(ws + off); off += (size_t)M_ * C_ * 2;
    __hip_bfloat16* attb = (__hip_bfloat16*)(ws + off); off += (size_t)M_ * C_ * 2;
    __hip_bfloat16* fb   = (__hip_bfloat16*)(ws + qb_off);  // aliases qb..attb (dead then)
    __hip_bfloat16* wqT  = (__hip_bfloat16*)(ws + off); off += (size_t)C_ * C_ * 2;
    __hip_bfloat16* wkT  = (__hip_bfloat16*)(ws + off); off += (size_t)C_ * C_ * 2;
    __hip_bfloat16* wvT  = (__hip_bfloat16*)(ws + off); off += (size_t)C_ * C_ * 2;
    __hip_bfloat16* wpT  = (__hip_bfloat16*)(ws + off); off += (size_t)C_ * C_ * 2;
    __hip_bfloat16* wf1T = (__hip_bfloat16*)(ws + off); off += (size_t)C_ * F_ * 2;
    __hip_bfloat16* wf2T = (__hip_bfloat16*)(ws + off); off += (size_t)F_ * C_ * 2;
    __hip_bfloat16* wteB = (__hip_bfloat16*)(ws + off); off += (size_t)V_ * C_ * 2;
    float* partials = (float*)(ws + off);          off += (size_t)M_ * 4;

    float* logits = (float*)d_out;
    float* loss   = (float*)d_out + (size_t)M_ * V_;

    convert_bf16_kernel<<<(V_ * C_ + 255) / 256, 256, 0, stream>>>(wte, wteB, V_ * C_);
    embed_kernel<<<(M_ * C_) / 256, 256, 0, stream>>>(idx, wte, wpe, x);

    for (int l = 0; l < L_; l++) {
        ln_kernel<<<M_, 256, 0, stream>>>(x, ln1_w + l * C_, ln1_b + l * C_, h);

        transpose_bf16_kernel<<<dim3(C_ / 32, C_ / 32), dim3(32, 8), 0, stream>>>(
            Wq + (size_t)l * C_ * C_, wqT, C_, C_);
        transpose_bf16_kernel<<<dim3(C_ / 32, C_ / 32), dim3(32, 8), 0, stream>>>(
            Wk + (size_t)l * C_ * C_, wkT, C_, C_);
        transpose_bf16_kernel<<<dim3(C_ / 32, C_ / 32), dim3(32, 8), 0, stream>>>(
            Wv + (size_t)l * C_ * C_, wvT, C_, C_);

        gemm64_kernel<false, false, false, false, true><<<dim3(C_ / 64, M_ / 64), 64, 0, stream>>>(
            h, wqT, nullptr, nullptr, nullptr, qb, M_, C_, C_);
        gemm64_kernel<false, false, false, false, true><<<dim3(C_ / 64, M_ / 64), 64, 0, stream>>>(
            h, wkT, nullptr, nullptr, nullptr, kb, M_, C_, C_);
        gemm64_kernel<false, false, false, false, true><<<dim3(C_ / 64, M_ / 64), 64, 0, stream>>>(
            h, wvT, nullptr, nullptr, nullptr, vb, M_, C_, C_);

        attn_flash_kernel<<<dim3(T_ / 64, H_, B_), 256, 0, stream>>>(qb, kb, vb, attb);

        transpose_bf16_kernel<<<dim3(C_ / 32, C_ / 32), dim3(32, 8), 0, stream>>>(
            projW + (size_t)l * C_ * C_, wpT, C_, C_);
        gemm64_kernel<true, true, false, true, false><<<dim3(C_ / 64, M_ / 64), 64, 0, stream>>>(
            attb, wpT, projb + l * C_, x, x, nullptr, M_, C_, C_);

        ln_kernel<<<M_, 256, 0, stream>>>(x, ln2_w + l * C_, ln2_b + l * C_, h);

        transpose_bf16_kernel<<<dim3(F_ / 32, C_ / 32), dim3(32, 8), 0, stream>>>(
            fc1W + (size_t)l * C_ * F_, wf1T, C_, F_);
        gemm64_kernel<true, false, true, false, true><<<dim3(F_ / 64, M_ / 64), 64, 0, stream>>>(
            h, wf1T, fc1b + l * F_, nullptr, nullptr, fb, M_, F_, C_);

        transpose_bf16_kernel<<<dim3(C_ / 32, F_ / 32), dim3(32, 8), 0, stream>>>(
            fc2W + (size_t)l * F_ * C_, wf2T, F_, C_);
        gemm64_kernel<true, true, false, true, false><<<dim3(C_ / 64, M_ / 64), 64, 0, stream>>>(
            fb, wf2T, fc2b + l * C_, x, x, nullptr, M_, C_, F_);
    }

    ln_kernel<<<M_, 256, 0, stream>>>(x, lnfw, lnfb, h);
    gemm64_kernel<true, false, false, true, false><<<dim3(V_ / 64, M_ / 64), 64, 0, stream>>>(
        h, wteB, lm_b, nullptr, logits, nullptr, M_, V_, C_);

    loss_rows_kernel<<<M_, 256, 0, stream>>>(logits, targets, partials);
    loss_reduce_kernel<<<1, 256, 0, stream>>>(partials, loss);
}

// Round 3
// 1529.299 us; speedup vs baseline: 4.8179x; 1.6317x over previous
//
#include <hip/hip_runtime.h>
#include <hip/hip_bf16.h>

typedef short bf16x8 __attribute__((ext_vector_type(8)));
typedef unsigned short u16x8 __attribute__((ext_vector_type(8)));
typedef float f32x4 __attribute__((ext_vector_type(4)));

#define B_ 4
#define T_ 1024
#define V_ 1024
#define C_ 768
#define H_ 12
#define HS_ 64
#define L_ 6
#define F_ 3072
#define M_ (B_ * T_)   // 4096 rows
#define QKV_ 2304      // fused q|k|v width

__device__ inline float b2f(unsigned short u) {
    return __uint_as_float(((unsigned int)u) << 16);
}
__device__ inline unsigned short f2bbits(float f) {
    __hip_bfloat16 h = __float2bfloat16(f);
    return *(unsigned short*)&h;
}
__device__ inline void load_lds_16(const void* g, void* l) {
    __builtin_amdgcn_global_load_lds(
        (const __attribute__((address_space(1))) unsigned int*)g,
        (__attribute__((address_space(3))) unsigned int*)l, 16, 0, 0);
}

// ---------------- elementwise / embedding ----------------
__global__ void convert_bf16_kernel(const float* __restrict__ in,
                                    __hip_bfloat16* __restrict__ out, int n) {
    int i = blockIdx.x * 256 + threadIdx.x;
    if (i < n) out[i] = __float2bfloat16(in[i]);
}

__global__ void embed_kernel(const int* __restrict__ idx,
                             const float* __restrict__ wte,
                             const float* __restrict__ wpe,
                             float* __restrict__ x) {
    int i = blockIdx.x * 256 + threadIdx.x;  // 0 .. M_*C_-1
    int row = i / C_;
    int c = i - row * C_;
    int t = row & (T_ - 1);
    x[i] = wte[(size_t)idx[row] * C_ + c] + wpe[(size_t)t * C_ + c];
}

// ---------------- layernorm (row of 768, block 256) ----------------
__global__ void ln_kernel(const float* __restrict__ x,
                          const float* __restrict__ w,
                          const float* __restrict__ b,
                          __hip_bfloat16* __restrict__ out) {
    int row = blockIdx.x, tid = threadIdx.x;
    const float* xr = x + (size_t)row * C_;
    float v0 = xr[tid], v1 = xr[tid + 256], v2 = xr[tid + 512];
    __shared__ float red[256];
    red[tid] = v0 + v1 + v2;
    __syncthreads();
    for (int s = 128; s; s >>= 1) {
        if (tid < s) red[tid] += red[tid + s];
        __syncthreads();
    }
    float mean = red[0] * (1.0f / C_);
    __syncthreads();
    float d0 = v0 - mean, d1 = v1 - mean, d2 = v2 - mean;
    red[tid] = d0 * d0 + d1 * d1 + d2 * d2;
    __syncthreads();
    for (int s = 128; s; s >>= 1) {
        if (tid < s) red[tid] += red[tid + s];
        __syncthreads();
    }
    float rstd = rsqrtf(red[0] * (1.0f / C_) + 1e-5f);
    __hip_bfloat16* o = out + (size_t)row * C_;
    o[tid]       = __float2bfloat16(d0 * rstd * w[tid]       + b[tid]);
    o[tid + 256] = __float2bfloat16(d1 * rstd * w[tid + 256] + b[tid + 256]);
    o[tid + 512] = __float2bfloat16(d2 * rstd * w[tid + 512] + b[tid + 512]);
}

// ---------------- transpose-convert W[K][N] f32 -> WT[N][K] bf16 ----------------
__global__ void transpose_bf16_kernel(const float* __restrict__ W,
                                      __hip_bfloat16* __restrict__ WT,
                                      int K, int N) {
    __shared__ float tile[32][33];
    int n0 = blockIdx.x * 32, k0 = blockIdx.y * 32;
    int tx = threadIdx.x, ty = threadIdx.y;  // 32 x 8
    #pragma unroll
    for (int i = 0; i < 4; i++)
        tile[ty + 8 * i][tx] = W[(size_t)(k0 + ty + 8 * i) * N + n0 + tx];
    __syncthreads();
    #pragma unroll
    for (int i = 0; i < 4; i++)
        WT[(size_t)(n0 + ty + 8 * i) * K + k0 + tx] =
            __float2bfloat16(tile[tx][ty + 8 * i]);
}

// ---------------- MFMA GEMM (m97 structure): 128x128 tile, BK=64, 4 waves ----
// A [M][K] bf16, WT [N][K] bf16. 1-D grid of (M/128)*(N/128), XCD-swizzled.
template <bool BIAS, bool RES, bool RELU, bool OUTF, bool OUTB>
__global__ __launch_bounds__(256) void gemm128_kernel(
    const __hip_bfloat16* __restrict__ A,
    const __hip_bfloat16* __restrict__ WT,
    const float* __restrict__ bias,
    const float* __restrict__ res,
    float* __restrict__ outF,
    __hip_bfloat16* __restrict__ outB,
    int M, int N, int K, int nbx) {
    __shared__ __align__(16) short As[128 * 64];
    __shared__ __align__(16) short Bs[128 * 64];
    int tid = threadIdx.x;
    int lane = tid & 63;
    int w = tid >> 6;                 // wave 0..3
    int l15 = lane & 15, l4 = lane >> 4;

    // XCD-aware bijective swizzle (all grids here are %8==0)
    int nwg = gridDim.x;
    int bid = blockIdx.x;
    int sbid = (bid & 7) * (nwg >> 3) + (bid >> 3);
    int bx = sbid % nbx, by = sbid / nbx;
    int row0 = by * 128, col0 = bx * 128;

    int wr = w >> 1, wc = w & 1;      // wave quadrant

    // staging: wave w covers rows w*32 .. w*32+31 (4 issues x 8 rows)
    int rA = w * 32 + (lane >> 3);
    int cA = (lane & 7) * 8;
    const char* Ag = (const char*)A + ((size_t)(row0 + rA) * K + cA) * 2;
    const char* Bg = (const char*)WT + ((size_t)(col0 + rA) * K + cA) * 2;
    char* AsW = (char*)As + w * 4096;
    char* BsW = (char*)Bs + w * 4096;

    f32x4 acc[4][4] = {};

    for (int k0 = 0; k0 < K; k0 += 64) {
        const char* Agk = Ag + k0 * 2;
        const char* Bgk = Bg + k0 * 2;
        #pragma unroll
        for (int i = 0; i < 4; i++) {
            load_lds_16(Agk + (size_t)i * 8 * K * 2, AsW + i * 1024);
            load_lds_16(Bgk + (size_t)i * 8 * K * 2, BsW + i * 1024);
        }
        __syncthreads();
        #pragma unroll
        for (int kk = 0; kk < 2; kk++) {
            bf16x8 a[4], b[4];
            #pragma unroll
            for (int i = 0; i < 4; i++)
                a[i] = *(const bf16x8*)((const char*)As +
                        ((wr * 64 + i * 16 + l15) * 64 + kk * 32 + l4 * 8) * 2);
            #pragma unroll
            for (int j = 0; j < 4; j++)
                b[j] = *(const bf16x8*)((const char*)Bs +
                        ((wc * 64 + j * 16 + l15) * 64 + kk * 32 + l4 * 8) * 2);
            #pragma unroll
            for (int i = 0; i < 4; i++)
                #pragma unroll
                for (int j = 0; j < 4; j++)
                    acc[i][j] = __builtin_amdgcn_mfma_f32_16x16x32_bf16(
                        a[i], b[j], acc[i][j], 0, 0, 0);
        }
        __syncthreads();
    }

    int rbase = l4 * 4;
    #pragma unroll
    for (int i = 0; i < 4; i++) {
        #pragma unroll
        for (int j = 0; j < 4; j++) {
            int col = col0 + wc * 64 + j * 16 + l15;
            float bv = BIAS ? bias[col] : 0.0f;
            #pragma unroll
            for (int r = 0; r < 4; r++) {
                int row = row0 + wr * 64 + i * 16 + rbase + r;
                size_t off = (size_t)row * N + col;
                float v = acc[i][j][r] + bv;
                if (RES) v += res[off];
                if (RELU) v = fmaxf(v, 0.0f);
                if (OUTF) outF[off] = v;
                if (OUTB) outB[off] = __float2bfloat16(v);
            }
        }
    }
}

// ---------------- flash attention: block = (b, h, 64 q rows), 4 waves ----------
// reads fused qkv buffer [M][2304] (q | k | v), writes attb [M][768]
__global__ __launch_bounds__(256) void attn_flash_kernel(
    const __hip_bfloat16* __restrict__ qkvb,
    __hip_bfloat16* __restrict__ attb) {
    int tid = threadIdx.x;
    int lane = tid & 63;
    int w = tid >> 6;               // wave 0..3
    int l15 = lane & 15;
    int l4 = lane >> 4;             // 0..3
    int qb0 = blockIdx.x * 64;
    int h = blockIdx.y;
    int b = blockIdx.z;

    __shared__ __align__(16) unsigned short Ks[64 * 64];      // swizzled [key][d]
    __shared__ __align__(16) unsigned short Vt[64 * 64];      // swizzled [d][key]
    __shared__ __align__(16) unsigned short Ps[4 * 16 * 64];  // per-wave [q][key]

    const unsigned short* qkv = (const unsigned short*)qkvb;
    const unsigned short* Qg = qkv + (size_t)(b * T_ + qb0) * QKV_ + h * HS_;
    const unsigned short* Kg = qkv + (size_t)b * T_ * QKV_ + C_ + h * HS_;
    const unsigned short* Vg = qkv + (size_t)b * T_ * QKV_ + 2 * C_ + h * HS_;

    // Q fragments (A operand): lane holds Q[row=l15][d = kk*32 + l4*8 + e]
    bf16x8 qfrag[2];
    {
        const short* qrow = (const short*)Qg + (size_t)(w * 16 + l15) * QKV_;
        qfrag[0] = *(const bf16x8*)(qrow + l4 * 8);
        qfrag[1] = *(const bf16x8*)(qrow + 32 + l4 * 8);
    }

    f32x4 o_acc[4] = {};
    float m_run[4], l_run[4];
    #pragma unroll
    for (int r = 0; r < 4; r++) { m_run[r] = -1e30f; l_run[r] = 0.0f; }

    unsigned short* Pw = Ps + w * 16 * 64;
    int nkb = blockIdx.x + 1;

    for (int kbi = 0; kbi < nkb; ++kbi) {
        int k0 = kbi * 64;
        __syncthreads();
        // ---- stage K (swizzled) and V (transposed+swizzled) ----
        {
            int key = tid >> 3, ch = tid & 7;
            #pragma unroll
            for (int it = 0; it < 2; ++it) {
                int ky = key + it * 32;
                u16x8 kv = *(const u16x8*)(Kg + (size_t)(k0 + ky) * QKV_ + ch * 8);
                int byteoff = ky * 128 + ((ch * 16) ^ ((ky & 7) << 4));
                *(u16x8*)((char*)Ks + byteoff) = kv;

                u16x8 vv = *(const u16x8*)(Vg + (size_t)(k0 + ky) * QKV_ + ch * 8);
                #pragma unroll
                for (int e = 0; e < 8; ++e) {
                    int d = ch * 8 + e;
                    int slot = (d ^ (d >> 3)) & 7;
                    int boff = d * 128 + ((ky * 2) ^ (slot << 4));
                    *(unsigned short*)((char*)Vt + boff) = (unsigned short)vv[e];
                }
            }
        }
        __syncthreads();

        // ---- S = Q K^T ----
        f32x4 s[4] = {};
        #pragma unroll
        for (int kk = 0; kk < 2; ++kk) {
            #pragma unroll
            for (int nt = 0; nt < 4; ++nt) {
                int key = nt * 16 + l15;
                int boff = key * 128 + (((l4 * 16) + kk * 64) ^ ((key & 7) << 4));
                bf16x8 kf = *(const bf16x8*)((char*)Ks + boff);
                s[nt] = __builtin_amdgcn_mfma_f32_16x16x32_bf16(qfrag[kk], kf, s[nt], 0, 0, 0);
            }
        }

        // ---- scale + causal mask ----
        bool last = (kbi == nkb - 1);
        #pragma unroll
        for (int nt = 0; nt < 4; ++nt)
            #pragma unroll
            for (int r = 0; r < 4; ++r) {
                float v = s[nt][r] * 0.125f;
                if (last) {
                    int key = k0 + nt * 16 + l15;
                    int q = qb0 + w * 16 + l4 * 4 + r;
                    if (key > q) v = -1e30f;
                }
                s[nt][r] = v;
            }

        // ---- online softmax (per q-row r, 16-lane group reduce) ----
        #pragma unroll
        for (int r = 0; r < 4; ++r) {
            float mx = fmaxf(fmaxf(s[0][r], s[1][r]), fmaxf(s[2][r], s[3][r]));
            #pragma unroll
            for (int o = 8; o; o >>= 1) mx = fmaxf(mx, __shfl_xor(mx, o));
            float mnew = fmaxf(m_run[r], mx);
            float alpha = __expf(m_run[r] - mnew);
            m_run[r] = mnew;
            float rs = 0.0f;
            #pragma unroll
            for (int nt = 0; nt < 4; ++nt) {
                float p = __expf(s[nt][r] - mnew);
                s[nt][r] = p;
                rs += p;
            }
            #pragma unroll
            for (int o = 8; o; o >>= 1) rs += __shfl_xor(rs, o);
            l_run[r] = l_run[r] * alpha + rs;
            #pragma unroll
            for (int nt = 0; nt < 4; ++nt) o_acc[nt][r] *= alpha;
        }

        // ---- write P to per-wave LDS (C layout -> swizzled [q][key]) ----
        #pragma unroll
        for (int nt = 0; nt < 4; ++nt)
            #pragma unroll
            for (int r = 0; r < 4; ++r) {
                int q = l4 * 4 + r;
                int col = nt * 16 + l15;
                int slot = (q ^ (q >> 3)) & 7;
                int boff = q * 128 + ((col * 2) ^ (slot << 4));
                *(unsigned short*)((char*)Pw + boff) = f2bbits(s[nt][r]);
            }

        // ---- O += P V ----
        #pragma unroll
        for (int kk = 0; kk < 2; ++kk) {
            int q = l15;
            int pslot = (q ^ (q >> 3)) & 7;
            int pboff = q * 128 + (((l4 * 16) + kk * 64) ^ (pslot << 4));
            bf16x8 pf = *(const bf16x8*)((char*)Pw + pboff);
            #pragma unroll
            for (int nt = 0; nt < 4; ++nt) {
                int d = nt * 16 + l15;
                int dslot = (d ^ (d >> 3)) & 7;
                int vboff = d * 128 + (((l4 * 16) + kk * 64) ^ (dslot << 4));
                bf16x8 vf = *(const bf16x8*)((char*)Vt + vboff);
                o_acc[nt] = __builtin_amdgcn_mfma_f32_16x16x32_bf16(pf, vf, o_acc[nt], 0, 0, 0);
            }
        }
    }

    // ---- epilogue: O /= l, write bf16 ----
    unsigned short* Og = (unsigned short*)attb + (size_t)(b * T_ + qb0) * C_ + h * HS_;
    #pragma unroll
    for (int r = 0; r < 4; ++r) {
        float inv = 1.0f / l_run[r];
        #pragma unroll
        for (int nt = 0; nt < 4; ++nt) {
            float val = o_acc[nt][r] * inv;
            Og[(size_t)(w * 16 + l4 * 4 + r) * C_ + nt * 16 + l15] = f2bbits(val);
        }
    }
}

// ---------------- loss ----------------
__global__ void loss_rows_kernel(const float* __restrict__ logits,
                                 const int* __restrict__ targets,
                                 float* __restrict__ partials) {
    int row = blockIdx.x, tid = threadIdx.x;
    const float* lr = logits + (size_t)row * V_;
    __shared__ float red[256];
    float mx = -1e30f;
    for (int i = tid; i < V_; i += 256) mx = fmaxf(mx, lr[i]);
    red[tid] = mx;
    __syncthreads();
    for (int s = 128; s; s >>= 1) {
        if (tid < s) red[tid] = fmaxf(red[tid], red[tid + s]);
        __syncthreads();
    }
    mx = red[0];
    __syncthreads();
    float sum = 0.0f;
    for (int i = tid; i < V_; i += 256) sum += __expf(lr[i] - mx);
    red[tid] = sum;
    __syncthreads();
    for (int s = 128; s; s >>= 1) {
        if (tid < s) red[tid] += red[tid + s];
        __syncthreads();
    }
    if (tid == 0) {
        float lse = mx + __logf(red[0]);
        partials[row] = lse - lr[targets[row]];
    }
}

__global__ void loss_reduce_kernel(const float* __restrict__ partials,
                                   float* __restrict__ out) {
    int tid = threadIdx.x;
    float s = 0.0f;
    for (int i = tid; i < M_; i += 256) s += partials[i];
    __shared__ float red[256];
    red[tid] = s;
    __syncthreads();
    for (int st = 128; st; st >>= 1) {
        if (tid < st) red[tid] += red[tid + st];
        __syncthreads();
    }
    if (tid == 0) out[0] = red[0] * (1.0f / M_);
}

// ---------------- launch ----------------
extern "C" void kernel_launch(void* const* d_in, const int* in_sizes, int n_in,
                              void* d_out, int out_size, void* d_ws, size_t ws_size,
                              hipStream_t stream) {
    const int*   idx     = (const int*)d_in[0];
    const int*   targets = (const int*)d_in[1];
    const float* wte     = (const float*)d_in[2];
    const float* wpe     = (const float*)d_in[3];
    const float* lm_b    = (const float*)d_in[4];
    const float* ln1_w   = (const float*)d_in[5];
    const float* ln1_b   = (const float*)d_in[6];
    const float* Wq      = (const float*)d_in[7];
    const float* Wk      = (const float*)d_in[8];
    const float* Wv      = (const float*)d_in[9];
    const float* projW   = (const float*)d_in[10];
    const float* projb   = (const float*)d_in[11];
    const float* ln2_w   = (const float*)d_in[12];
    const float* ln2_b   = (const float*)d_in[13];
    const float* fc1W    = (const float*)d_in[14];
    const float* fc1b    = (const float*)d_in[15];
    const float* fc2W    = (const float*)d_in[16];
    const float* fc2b    = (const float*)d_in[17];
    const float* lnfw    = (const float*)d_in[18];
    const float* lnfb    = (const float*)d_in[19];

    char* ws = (char*)d_ws;
    size_t off = 0;
    float* x = (float*)(ws + off);                 off += (size_t)M_ * C_ * 4;
    __hip_bfloat16* h    = (__hip_bfloat16*)(ws + off); off += (size_t)M_ * C_ * 2;
    size_t qkv_off = off;
    __hip_bfloat16* qkvb = (__hip_bfloat16*)(ws + off); off += (size_t)M_ * QKV_ * 2;
    __hip_bfloat16* attb = (__hip_bfloat16*)(ws + off); off += (size_t)M_ * C_ * 2;
    __hip_bfloat16* fb   = (__hip_bfloat16*)(ws + qkv_off);  // aliases qkvb+attb (dead then)
    __hip_bfloat16* qkvT = (__hip_bfloat16*)(ws + off); off += (size_t)QKV_ * C_ * 2;
    __hip_bfloat16* wpT  = (__hip_bfloat16*)(ws + off); off += (size_t)C_ * C_ * 2;
    __hip_bfloat16* wf1T = (__hip_bfloat16*)(ws + off); off += (size_t)C_ * F_ * 2;
    __hip_bfloat16* wf2T = (__hip_bfloat16*)(ws + off); off += (size_t)F_ * C_ * 2;
    __hip_bfloat16* wteB = (__hip_bfloat16*)(ws + off); off += (size_t)V_ * C_ * 2;
    float* partials = (float*)(ws + off);          off += (size_t)M_ * 4;

    float* logits = (float*)d_out;
    float* loss   = (float*)d_out + (size_t)M_ * V_;

    convert_bf16_kernel<<<(V_ * C_ + 255) / 256, 256, 0, stream>>>(wte, wteB, V_ * C_);
    embed_kernel<<<(M_ * C_) / 256, 256, 0, stream>>>(idx, wte, wpe, x);

    for (int l = 0; l < L_; l++) {
        ln_kernel<<<M_, 256, 0, stream>>>(x, ln1_w + l * C_, ln1_b + l * C_, h);

        transpose_bf16_kernel<<<dim3(C_ / 32, C_ / 32), dim3(32, 8), 0, stream>>>(
            Wq + (size_t)l * C_ * C_, qkvT, C_, C_);
        transpose_bf16_kernel<<<dim3(C_ / 32, C_ / 32), dim3(32, 8), 0, stream>>>(
            Wk + (size_t)l * C_ * C_, qkvT + (size_t)C_ * C_, C_, C_);
        transpose_bf16_kernel<<<dim3(C_ / 32, C_ / 32), dim3(32, 8), 0, stream>>>(
            Wv + (size_t)l * C_ * C_, qkvT + (size_t)2 * C_ * C_, C_, C_);

        // fused QKV GEMM: [M][768] x [768][2304] -> [M][2304]
        gemm128_kernel<false, false, false, false, true>
            <<<(M_ / 128) * (QKV_ / 128), 256, 0, stream>>>(
            h, qkvT, nullptr, nullptr, nullptr, qkvb, M_, QKV_, C_, QKV_ / 128);

        attn_flash_kernel<<<dim3(T_ / 64, H_, B_), 256, 0, stream>>>(qkvb, attb);

        transpose_bf16_kernel<<<dim3(C_ / 32, C_ / 32), dim3(32, 8), 0, stream>>>(
            projW + (size_t)l * C_ * C_, wpT, C_, C_);
        gemm128_kernel<true, true, false, true, false>
            <<<(M_ / 128) * (C_ / 128), 256, 0, stream>>>(
            attb, wpT, projb + l * C_, x, x, nullptr, M_, C_, C_, C_ / 128);

        ln_kernel<<<M_, 256, 0, stream>>>(x, ln2_w + l * C_, ln2_b + l * C_, h);

        transpose_bf16_kernel<<<dim3(F_ / 32, C_ / 32), dim3(32, 8), 0, stream>>>(
            fc1W + (size_t)l * C_ * F_, wf1T, C_, F_);
        gemm128_kernel<true, false, true, false, true>
            <<<(M_ / 128) * (F_ / 128), 256, 0, stream>>>(
            h, wf1T, fc1b + l * F_, nullptr, nullptr, fb, M_, F_, C_, F_ / 128);

        transpose_bf16_kernel<<<dim3(C_ / 32, F_ / 32), dim3(32, 8), 0, stream>>>(
            fc2W + (size_t)l * F_ * C_, wf2T, F_, C_);
        gemm128_kernel<true, true, false, true, false>
            <<<(M_ / 128) * (C_ / 128), 256, 0, stream>>>(
            fb, wf2T, fc2b + l * C_, x, x, nullptr, M_, C_, F_, C_ / 128);
    }

    ln_kernel<<<M_, 256, 0, stream>>>(x, lnfw, lnfb, h);
    gemm128_kernel<true, false, false, true, false>
        <<<(M_ / 128) * (V_ / 128), 256, 0, stream>>>(
        h, wteB, lm_b, nullptr, logits, nullptr, M_, V_, C_, V_ / 128);

    loss_rows_kernel<<<M_, 256, 0, stream>>>(logits, targets, partials);
    loss_reduce_kernel<<<1, 256, 0, stream>>>(partials, loss);
}

// Round 4
// 1344.318 us; speedup vs baseline: 5.4808x; 1.1376x over previous
//
#include <hip/hip_runtime.h>
#include <hip/hip_bf16.h>

typedef short bf16x8 __attribute__((ext_vector_type(8)));
typedef unsigned short u16x8 __attribute__((ext_vector_type(8)));
typedef float f32x4 __attribute__((ext_vector_type(4)));

#define B_ 4
#define T_ 1024
#define V_ 1024
#define C_ 768
#define H_ 12
#define HS_ 64
#define L_ 6
#define F_ 3072
#define M_ (B_ * T_)   // 4096 rows
#define QKV_ 2304      // fused q|k|v width

__device__ inline float b2f(unsigned short u) {
    return __uint_as_float(((unsigned int)u) << 16);
}
__device__ inline unsigned short f2bbits(float f) {
    __hip_bfloat16 h = __float2bfloat16(f);
    return *(unsigned short*)&h;
}
__device__ inline void load_lds_16(const void* g, void* l) {
    __builtin_amdgcn_global_load_lds(
        (const __attribute__((address_space(1))) unsigned int*)g,
        (__attribute__((address_space(3))) unsigned int*)l, 16, 0, 0);
}

// ---------------- elementwise / embedding ----------------
__global__ void convert_bf16_kernel(const float* __restrict__ in,
                                    __hip_bfloat16* __restrict__ out, int n) {
    int i = blockIdx.x * 256 + threadIdx.x;
    if (i < n) out[i] = __float2bfloat16(in[i]);
}

__global__ void embed_kernel(const int* __restrict__ idx,
                             const float* __restrict__ wte,
                             const float* __restrict__ wpe,
                             float* __restrict__ x) {
    int i = blockIdx.x * 256 + threadIdx.x;  // 0 .. M_*C_-1
    int row = i / C_;
    int c = i - row * C_;
    int t = row & (T_ - 1);
    x[i] = wte[(size_t)idx[row] * C_ + c] + wpe[(size_t)t * C_ + c];
}

// ---------------- layernorm (row of 768, block 256) ----------------
__global__ void ln_kernel(const float* __restrict__ x,
                          const float* __restrict__ w,
                          const float* __restrict__ b,
                          __hip_bfloat16* __restrict__ out) {
    int row = blockIdx.x, tid = threadIdx.x;
    const float* xr = x + (size_t)row * C_;
    float v0 = xr[tid], v1 = xr[tid + 256], v2 = xr[tid + 512];
    __shared__ float red[256];
    red[tid] = v0 + v1 + v2;
    __syncthreads();
    for (int s = 128; s; s >>= 1) {
        if (tid < s) red[tid] += red[tid + s];
        __syncthreads();
    }
    float mean = red[0] * (1.0f / C_);
    __syncthreads();
    float d0 = v0 - mean, d1 = v1 - mean, d2 = v2 - mean;
    red[tid] = d0 * d0 + d1 * d1 + d2 * d2;
    __syncthreads();
    for (int s = 128; s; s >>= 1) {
        if (tid < s) red[tid] += red[tid + s];
        __syncthreads();
    }
    float rstd = rsqrtf(red[0] * (1.0f / C_) + 1e-5f);
    __hip_bfloat16* o = out + (size_t)row * C_;
    o[tid]       = __float2bfloat16(d0 * rstd * w[tid]       + b[tid]);
    o[tid + 256] = __float2bfloat16(d1 * rstd * w[tid + 256] + b[tid + 256]);
    o[tid + 512] = __float2bfloat16(d2 * rstd * w[tid + 512] + b[tid + 512]);
}

// ---------------- transpose-convert W[K][N] f32 -> WT[N][K] bf16 ----------------
// generic, layered via blockIdx.z
__global__ void transpose_bf16_kernel(const float* __restrict__ W,
                                      __hip_bfloat16* __restrict__ WT,
                                      int K, int N,
                                      size_t sStride, size_t dStride) {
    int l = blockIdx.z;
    W += (size_t)l * sStride;
    WT += (size_t)l * dStride;
    __shared__ float tile[32][33];
    int n0 = blockIdx.x * 32, k0 = blockIdx.y * 32;
    int tx = threadIdx.x, ty = threadIdx.y;  // 32 x 8
    #pragma unroll
    for (int i = 0; i < 4; i++)
        tile[ty + 8 * i][tx] = W[(size_t)(k0 + ty + 8 * i) * N + n0 + tx];
    __syncthreads();
    #pragma unroll
    for (int i = 0; i < 4; i++)
        WT[(size_t)(n0 + ty + 8 * i) * K + k0 + tx] =
            __float2bfloat16(tile[tx][ty + 8 * i]);
}

// qkv: blockIdx.z = l*3 + which, dst packed [QKV][C] per layer
__global__ void transpose_qkv_kernel(const float* __restrict__ Wq,
                                     const float* __restrict__ Wk,
                                     const float* __restrict__ Wv,
                                     __hip_bfloat16* __restrict__ dst) {
    int z = blockIdx.z;
    int l = z / 3, which = z % 3;
    const float* W = (which == 0 ? Wq : which == 1 ? Wk : Wv) + (size_t)l * C_ * C_;
    __hip_bfloat16* WT = dst + (size_t)l * QKV_ * C_ + (size_t)which * C_ * C_;
    __shared__ float tile[32][33];
    int n0 = blockIdx.x * 32, k0 = blockIdx.y * 32;
    int tx = threadIdx.x, ty = threadIdx.y;
    #pragma unroll
    for (int i = 0; i < 4; i++)
        tile[ty + 8 * i][tx] = W[(size_t)(k0 + ty + 8 * i) * C_ + n0 + tx];
    __syncthreads();
    #pragma unroll
    for (int i = 0; i < 4; i++)
        WT[(size_t)(n0 + ty + 8 * i) * C_ + k0 + tx] =
            __float2bfloat16(tile[tx][ty + 8 * i]);
}

// ---------------- MFMA GEMM: 64x128 tile, BK=64, dbuf LDS + prefetch ----------
// A [M][K] bf16, WT [N][K] bf16. 1-D grid (M/64)*(N/128), XCD-swizzled.
// 4 waves, each owns a 32x64 quadrant (wr = w>>1 row-half, wc = w&1 col-half).
template <bool BIAS, bool RES, bool RELU, bool OUTF, bool OUTB>
__global__ __launch_bounds__(256) void gemm64x128_kernel(
    const __hip_bfloat16* __restrict__ A,
    const __hip_bfloat16* __restrict__ WT,
    const float* __restrict__ bias,
    const float* __restrict__ res,
    float* __restrict__ outF,
    __hip_bfloat16* __restrict__ outB,
    int M, int N, int K, int nbx) {
    __shared__ __align__(16) short As[2 * 64 * 64];    // 2 x 8 KB
    __shared__ __align__(16) short Bs[2 * 128 * 64];   // 2 x 16 KB
    int tid = threadIdx.x;
    int lane = tid & 63;
    int w = tid >> 6;
    int l15 = lane & 15, l4 = lane >> 4;

    // XCD-aware bijective swizzle (all grids here are %8==0)
    int nwg = gridDim.x;
    int bid = blockIdx.x;
    int sbid = (bid & 7) * (nwg >> 3) + (bid >> 3);
    int bx = sbid % nbx, by = sbid / nbx;
    int row0 = by * 64, col0 = bx * 128;

    int wr = w >> 1, wc = w & 1;

    // staging addresses: thread covers row tid>>3 (+32*i), col (tid&7)*8
    int rr = tid >> 3;
    int cc = (tid & 7) * 8;
    const char* Ag = (const char*)A + ((size_t)(row0 + rr) * K + cc) * 2;
    const char* Bg = (const char*)WT + ((size_t)(col0 + rr) * K + cc) * 2;

    f32x4 acc[2][4] = {};
    int ktiles = K >> 6;

    auto stage = [&](int buf, int k0) {
        const char* Agk = Ag + (size_t)k0 * 2;
        const char* Bgk = Bg + (size_t)k0 * 2;
        #pragma unroll
        for (int i = 0; i < 2; i++)
            load_lds_16(Agk + (size_t)i * 32 * K * 2,
                        (char*)As + buf * 8192 + i * 4096 + w * 1024);
        #pragma unroll
        for (int i = 0; i < 4; i++)
            load_lds_16(Bgk + (size_t)i * 32 * K * 2,
                        (char*)Bs + buf * 16384 + i * 4096 + w * 1024);
    };

    stage(0, 0);
    __syncthreads();
    int cur = 0;
    for (int t = 0; t < ktiles; ++t) {
        if (t + 1 < ktiles) stage(cur ^ 1, (t + 1) * 64);
        const char* Asb = (const char*)As + cur * 8192;
        const char* Bsb = (const char*)Bs + cur * 16384;
        #pragma unroll
        for (int kk = 0; kk < 2; kk++) {
            bf16x8 a[2], b[4];
            #pragma unroll
            for (int i = 0; i < 2; i++)
                a[i] = *(const bf16x8*)(Asb +
                        ((wr * 32 + i * 16 + l15) * 64 + kk * 32 + l4 * 8) * 2);
            #pragma unroll
            for (int j = 0; j < 4; j++)
                b[j] = *(const bf16x8*)(Bsb +
                        ((wc * 64 + j * 16 + l15) * 64 + kk * 32 + l4 * 8) * 2);
            #pragma unroll
            for (int i = 0; i < 2; i++)
                #pragma unroll
                for (int j = 0; j < 4; j++)
                    acc[i][j] = __builtin_amdgcn_mfma_f32_16x16x32_bf16(
                        a[i], b[j], acc[i][j], 0, 0, 0);
        }
        __syncthreads();   // drains prefetch vmem + guards buffer reuse
        cur ^= 1;
    }

    int rbase = l4 * 4;
    #pragma unroll
    for (int i = 0; i < 2; i++) {
        #pragma unroll
        for (int j = 0; j < 4; j++) {
            int col = col0 + wc * 64 + j * 16 + l15;
            float bv = BIAS ? bias[col] : 0.0f;
            #pragma unroll
            for (int r = 0; r < 4; r++) {
                int row = row0 + wr * 32 + i * 16 + rbase + r;
                size_t off = (size_t)row * N + col;
                float v = acc[i][j][r] + bv;
                if (RES) v += res[off];
                if (RELU) v = fmaxf(v, 0.0f);
                if (OUTF) outF[off] = v;
                if (OUTB) outB[off] = __float2bfloat16(v);
            }
        }
    }
}

// ---------------- flash attention: block = (b, h, 64 q rows), 4 waves ----------
__global__ __launch_bounds__(256) void attn_flash_kernel(
    const __hip_bfloat16* __restrict__ qkvb,
    __hip_bfloat16* __restrict__ attb) {
    int tid = threadIdx.x;
    int lane = tid & 63;
    int w = tid >> 6;
    int l15 = lane & 15;
    int l4 = lane >> 4;
    int qb0 = blockIdx.x * 64;
    int h = blockIdx.y;
    int b = blockIdx.z;

    __shared__ __align__(16) unsigned short Ks[64 * 64];
    __shared__ __align__(16) unsigned short Vt[64 * 64];
    __shared__ __align__(16) unsigned short Ps[4 * 16 * 64];

    const unsigned short* qkv = (const unsigned short*)qkvb;
    const unsigned short* Qg = qkv + (size_t)(b * T_ + qb0) * QKV_ + h * HS_;
    const unsigned short* Kg = qkv + (size_t)b * T_ * QKV_ + C_ + h * HS_;
    const unsigned short* Vg = qkv + (size_t)b * T_ * QKV_ + 2 * C_ + h * HS_;

    bf16x8 qfrag[2];
    {
        const short* qrow = (const short*)Qg + (size_t)(w * 16 + l15) * QKV_;
        qfrag[0] = *(const bf16x8*)(qrow + l4 * 8);
        qfrag[1] = *(const bf16x8*)(qrow + 32 + l4 * 8);
    }

    f32x4 o_acc[4] = {};
    float m_run[4], l_run[4];
    #pragma unroll
    for (int r = 0; r < 4; r++) { m_run[r] = -1e30f; l_run[r] = 0.0f; }

    unsigned short* Pw = Ps + w * 16 * 64;
    int nkb = blockIdx.x + 1;

    for (int kbi = 0; kbi < nkb; ++kbi) {
        int k0 = kbi * 64;
        __syncthreads();
        {
            int key = tid >> 3, ch = tid & 7;
            #pragma unroll
            for (int it = 0; it < 2; ++it) {
                int ky = key + it * 32;
                u16x8 kv = *(const u16x8*)(Kg + (size_t)(k0 + ky) * QKV_ + ch * 8);
                int byteoff = ky * 128 + ((ch * 16) ^ ((ky & 7) << 4));
                *(u16x8*)((char*)Ks + byteoff) = kv;

                u16x8 vv = *(const u16x8*)(Vg + (size_t)(k0 + ky) * QKV_ + ch * 8);
                #pragma unroll
                for (int e = 0; e < 8; ++e) {
                    int d = ch * 8 + e;
                    int slot = (d ^ (d >> 3)) & 7;
                    int boff = d * 128 + ((ky * 2) ^ (slot << 4));
                    *(unsigned short*)((char*)Vt + boff) = (unsigned short)vv[e];
                }
            }
        }
        __syncthreads();

        f32x4 s[4] = {};
        #pragma unroll
        for (int kk = 0; kk < 2; ++kk) {
            #pragma unroll
            for (int nt = 0; nt < 4; ++nt) {
                int key = nt * 16 + l15;
                int boff = key * 128 + (((l4 * 16) + kk * 64) ^ ((key & 7) << 4));
                bf16x8 kf = *(const bf16x8*)((char*)Ks + boff);
                s[nt] = __builtin_amdgcn_mfma_f32_16x16x32_bf16(qfrag[kk], kf, s[nt], 0, 0, 0);
            }
        }

        bool last = (kbi == nkb - 1);
        #pragma unroll
        for (int nt = 0; nt < 4; ++nt)
            #pragma unroll
            for (int r = 0; r < 4; ++r) {
                float v = s[nt][r] * 0.125f;
                if (last) {
                    int key = k0 + nt * 16 + l15;
                    int q = qb0 + w * 16 + l4 * 4 + r;
                    if (key > q) v = -1e30f;
                }
                s[nt][r] = v;
            }

        #pragma unroll
        for (int r = 0; r < 4; ++r) {
            float mx = fmaxf(fmaxf(s[0][r], s[1][r]), fmaxf(s[2][r], s[3][r]));
            #pragma unroll
            for (int o = 8; o; o >>= 1) mx = fmaxf(mx, __shfl_xor(mx, o));
            float mnew = fmaxf(m_run[r], mx);
            float alpha = __expf(m_run[r] - mnew);
            m_run[r] = mnew;
            float rs = 0.0f;
            #pragma unroll
            for (int nt = 0; nt < 4; ++nt) {
                float p = __expf(s[nt][r] - mnew);
                s[nt][r] = p;
                rs += p;
            }
            #pragma unroll
            for (int o = 8; o; o >>= 1) rs += __shfl_xor(rs, o);
            l_run[r] = l_run[r] * alpha + rs;
            #pragma unroll
            for (int nt = 0; nt < 4; ++nt) o_acc[nt][r] *= alpha;
        }

        #pragma unroll
        for (int nt = 0; nt < 4; ++nt)
            #pragma unroll
            for (int r = 0; r < 4; ++r) {
                int q = l4 * 4 + r;
                int col = nt * 16 + l15;
                int slot = (q ^ (q >> 3)) & 7;
                int boff = q * 128 + ((col * 2) ^ (slot << 4));
                *(unsigned short*)((char*)Pw + boff) = f2bbits(s[nt][r]);
            }

        #pragma unroll
        for (int kk = 0; kk < 2; ++kk) {
            int q = l15;
            int pslot = (q ^ (q >> 3)) & 7;
            int pboff = q * 128 + (((l4 * 16) + kk * 64) ^ (pslot << 4));
            bf16x8 pf = *(const bf16x8*)((char*)Pw + pboff);
            #pragma unroll
            for (int nt = 0; nt < 4; ++nt) {
                int d = nt * 16 + l15;
                int dslot = (d ^ (d >> 3)) & 7;
                int vboff = d * 128 + (((l4 * 16) + kk * 64) ^ (dslot << 4));
                bf16x8 vf = *(const bf16x8*)((char*)Vt + vboff);
                o_acc[nt] = __builtin_amdgcn_mfma_f32_16x16x32_bf16(pf, vf, o_acc[nt], 0, 0, 0);
            }
        }
    }

    unsigned short* Og = (unsigned short*)attb + (size_t)(b * T_ + qb0) * C_ + h * HS_;
    #pragma unroll
    for (int r = 0; r < 4; ++r) {
        float inv = 1.0f / l_run[r];
        #pragma unroll
        for (int nt = 0; nt < 4; ++nt) {
            float val = o_acc[nt][r] * inv;
            Og[(size_t)(w * 16 + l4 * 4 + r) * C_ + nt * 16 + l15] = f2bbits(val);
        }
    }
}

// ---------------- loss ----------------
__global__ void loss_rows_kernel(const float* __restrict__ logits,
                                 const int* __restrict__ targets,
                                 float* __restrict__ partials) {
    int row = blockIdx.x, tid = threadIdx.x;
    const float* lr = logits + (size_t)row * V_;
    __shared__ float red[256];
    float mx = -1e30f;
    for (int i = tid; i < V_; i += 256) mx = fmaxf(mx, lr[i]);
    red[tid] = mx;
    __syncthreads();
    for (int s = 128; s; s >>= 1) {
        if (tid < s) red[tid] = fmaxf(red[tid], red[tid + s]);
        __syncthreads();
    }
    mx = red[0];
    __syncthreads();
    float sum = 0.0f;
    for (int i = tid; i < V_; i += 256) sum += __expf(lr[i] - mx);
    red[tid] = sum;
    __syncthreads();
    for (int s = 128; s; s >>= 1) {
        if (tid < s) red[tid] += red[tid + s];
        __syncthreads();
    }
    if (tid == 0) {
        float lse = mx + __logf(red[0]);
        partials[row] = lse - lr[targets[row]];
    }
}

__global__ void loss_reduce_kernel(const float* __restrict__ partials,
                                   float* __restrict__ out) {
    int tid = threadIdx.x;
    float s = 0.0f;
    for (int i = tid; i < M_; i += 256) s += partials[i];
    __shared__ float red[256];
    red[tid] = s;
    __syncthreads();
    for (int st = 128; st; st >>= 1) {
        if (tid < st) red[tid] += red[tid + st];
        __syncthreads();
    }
    if (tid == 0) out[0] = red[0] * (1.0f / M_);
}

// ---------------- launch ----------------
extern "C" void kernel_launch(void* const* d_in, const int* in_sizes, int n_in,
                              void* d_out, int out_size, void* d_ws, size_t ws_size,
                              hipStream_t stream) {
    const int*   idx     = (const int*)d_in[0];
    const int*   targets = (const int*)d_in[1];
    const float* wte     = (const float*)d_in[2];
    const float* wpe     = (const float*)d_in[3];
    const float* lm_b    = (const float*)d_in[4];
    const float* ln1_w   = (const float*)d_in[5];
    const float* ln1_b   = (const float*)d_in[6];
    const float* Wq      = (const float*)d_in[7];
    const float* Wk      = (const float*)d_in[8];
    const float* Wv      = (const float*)d_in[9];
    const float* projW   = (const float*)d_in[10];
    const float* projb   = (const float*)d_in[11];
    const float* ln2_w   = (const float*)d_in[12];
    const float* ln2_b   = (const float*)d_in[13];
    const float* fc1W    = (const float*)d_in[14];
    const float* fc1b    = (const float*)d_in[15];
    const float* fc2W    = (const float*)d_in[16];
    const float* fc2b    = (const float*)d_in[17];
    const float* lnfw    = (const float*)d_in[18];
    const float* lnfb    = (const float*)d_in[19];

    char* ws = (char*)d_ws;
    size_t off = 0;
    float* x = (float*)(ws + off);                 off += (size_t)M_ * C_ * 4;
    __hip_bfloat16* h    = (__hip_bfloat16*)(ws + off); off += (size_t)M_ * C_ * 2;
    size_t qkv_off = off;
    __hip_bfloat16* qkvb = (__hip_bfloat16*)(ws + off); off += (size_t)M_ * QKV_ * 2;
    __hip_bfloat16* attb = (__hip_bfloat16*)(ws + off); off += (size_t)M_ * C_ * 2;
    __hip_bfloat16* fb   = (__hip_bfloat16*)(ws + qkv_off);  // aliases qkvb+attb
    __hip_bfloat16* wteB = (__hip_bfloat16*)(ws + off); off += (size_t)V_ * C_ * 2;
    float* partials = (float*)(ws + off);          off += (size_t)M_ * 4;

    // per-layer weight sizes (elements)
    const size_t QKV_SZ = (size_t)QKV_ * C_;
    const size_t WP_SZ  = (size_t)C_ * C_;
    const size_t F1_SZ  = (size_t)C_ * F_;
    const size_t F2_SZ  = (size_t)F_ * C_;
    size_t upfront_bytes = off + 2 * (size_t)L_ * (QKV_SZ + WP_SZ + F1_SZ + F2_SZ);
    bool upfront = ws_size >= upfront_bytes;
    int rep = upfront ? L_ : 1;

    __hip_bfloat16* qkvT0 = (__hip_bfloat16*)(ws + off); off += 2 * (size_t)rep * QKV_SZ;
    __hip_bfloat16* wpT0  = (__hip_bfloat16*)(ws + off); off += 2 * (size_t)rep * WP_SZ;
    __hip_bfloat16* wf1T0 = (__hip_bfloat16*)(ws + off); off += 2 * (size_t)rep * F1_SZ;
    __hip_bfloat16* wf2T0 = (__hip_bfloat16*)(ws + off); off += 2 * (size_t)rep * F2_SZ;

    float* logits = (float*)d_out;
    float* loss   = (float*)d_out + (size_t)M_ * V_;

    convert_bf16_kernel<<<(V_ * C_ + 255) / 256, 256, 0, stream>>>(wte, wteB, V_ * C_);
    embed_kernel<<<(M_ * C_) / 256, 256, 0, stream>>>(idx, wte, wpe, x);

    if (upfront) {
        transpose_qkv_kernel<<<dim3(C_ / 32, C_ / 32, 3 * L_), dim3(32, 8), 0, stream>>>(
            Wq, Wk, Wv, qkvT0);
        transpose_bf16_kernel<<<dim3(C_ / 32, C_ / 32, L_), dim3(32, 8), 0, stream>>>(
            projW, wpT0, C_, C_, WP_SZ, WP_SZ);
        transpose_bf16_kernel<<<dim3(F_ / 32, C_ / 32, L_), dim3(32, 8), 0, stream>>>(
            fc1W, wf1T0, C_, F_, F1_SZ, F1_SZ);
        transpose_bf16_kernel<<<dim3(C_ / 32, F_ / 32, L_), dim3(32, 8), 0, stream>>>(
            fc2W, wf2T0, F_, C_, F2_SZ, F2_SZ);
    }

    for (int l = 0; l < L_; l++) {
        __hip_bfloat16* qkvT = qkvT0 + (upfront ? (size_t)l * QKV_SZ : 0);
        __hip_bfloat16* wpT  = wpT0  + (upfront ? (size_t)l * WP_SZ : 0);
        __hip_bfloat16* wf1T = wf1T0 + (upfront ? (size_t)l * F1_SZ : 0);
        __hip_bfloat16* wf2T = wf2T0 + (upfront ? (size_t)l * F2_SZ : 0);

        ln_kernel<<<M_, 256, 0, stream>>>(x, ln1_w + l * C_, ln1_b + l * C_, h);

        if (!upfront)
            transpose_qkv_kernel<<<dim3(C_ / 32, C_ / 32, 3), dim3(32, 8), 0, stream>>>(
                Wq + (size_t)l * C_ * C_, Wk + (size_t)l * C_ * C_,
                Wv + (size_t)l * C_ * C_, qkvT);

        gemm64x128_kernel<false, false, false, false, true>
            <<<(M_ / 64) * (QKV_ / 128), 256, 0, stream>>>(
            h, qkvT, nullptr, nullptr, nullptr, qkvb, M_, QKV_, C_, QKV_ / 128);

        attn_flash_kernel<<<dim3(T_ / 64, H_, B_), 256, 0, stream>>>(qkvb, attb);

        if (!upfront)
            transpose_bf16_kernel<<<dim3(C_ / 32, C_ / 32, 1), dim3(32, 8), 0, stream>>>(
                projW + (size_t)l * C_ * C_, wpT, C_, C_, 0, 0);
        gemm64x128_kernel<true, true, false, true, false>
            <<<(M_ / 64) * (C_ / 128), 256, 0, stream>>>(
            attb, wpT, projb + l * C_, x, x, nullptr, M_, C_, C_, C_ / 128);

        ln_kernel<<<M_, 256, 0, stream>>>(x, ln2_w + l * C_, ln2_b + l * C_, h);

        if (!upfront)
            transpose_bf16_kernel<<<dim3(F_ / 32, C_ / 32, 1), dim3(32, 8), 0, stream>>>(
                fc1W + (size_t)l * C_ * F_, wf1T, C_, F_, 0, 0);
        gemm64x128_kernel<true, false, true, false, true>
            <<<(M_ / 64) * (F_ / 128), 256, 0, stream>>>(
            h, wf1T, fc1b + l * F_, nullptr, nullptr, fb, M_, F_, C_, F_ / 128);

        if (!upfront)
            transpose_bf16_kernel<<<dim3(C_ / 32, F_ / 32, 1), dim3(32, 8), 0, stream>>>(
                fc2W + (size_t)l * F_ * C_, wf2T, F_, C_, 0, 0);
        gemm64x128_kernel<true, true, false, true, false>
            <<<(M_ / 64) * (C_ / 128), 256, 0, stream>>>(
            fb, wf2T, fc2b + l * C_, x, x, nullptr, M_, C_, F_, C_ / 128);
    }

    ln_kernel<<<M_, 256, 0, stream>>>(x, lnfw, lnfb, h);
    gemm64x128_kernel<true, false, false, true, false>
        <<<(M_ / 64) * (V_ / 128), 256, 0, stream>>>(
        h, wteB, lm_b, nullptr, logits, nullptr, M_, V_, C_, V_ / 128);

    loss_rows_kernel<<<M_, 256, 0, stream>>>(logits, targets, partials);
    loss_reduce_kernel<<<1, 256, 0, stream>>>(partials, loss);
}

// Round 5
// 1170.560 us; speedup vs baseline: 6.2944x; 1.1484x over previous
//
#include <hip/hip_runtime.h>
#include <hip/hip_bf16.h>

typedef short bf16x8 __attribute__((ext_vector_type(8)));
typedef unsigned short u16x8 __attribute__((ext_vector_type(8)));
typedef float f32x4 __attribute__((ext_vector_type(4)));

#define B_ 4
#define T_ 1024
#define V_ 1024
#define C_ 768
#define H_ 12
#define HS_ 64
#define L_ 6
#define F_ 3072
#define M_ (B_ * T_)   // 4096 rows
#define QKV_ 2304      // fused q|k|v width

__device__ inline float b2f(unsigned short u) {
    return __uint_as_float(((unsigned int)u) << 16);
}
__device__ inline unsigned short f2bbits(float f) {
    __hip_bfloat16 h = __float2bfloat16(f);
    return *(unsigned short*)&h;
}
__device__ inline void load_lds_16(const void* g, void* l) {
    __builtin_amdgcn_global_load_lds(
        (const __attribute__((address_space(1))) unsigned int*)g,
        (__attribute__((address_space(3))) unsigned int*)l, 16, 0, 0);
}

// ---------------- elementwise / embedding ----------------
__global__ void convert_bf16_kernel(const float* __restrict__ in,
                                    __hip_bfloat16* __restrict__ out, int n) {
    int i = blockIdx.x * 256 + threadIdx.x;
    if (i < n) out[i] = __float2bfloat16(in[i]);
}

__global__ void embed_kernel(const int* __restrict__ idx,
                             const float* __restrict__ wte,
                             const float* __restrict__ wpe,
                             float* __restrict__ x) {
    int i = blockIdx.x * 256 + threadIdx.x;  // 0 .. M_*C_-1
    int row = i / C_;
    int c = i - row * C_;
    int t = row & (T_ - 1);
    x[i] = wte[(size_t)idx[row] * C_ + c] + wpe[(size_t)t * C_ + c];
}

// ---------------- layernorm (row of 768, block 256) ----------------
__global__ void ln_kernel(const float* __restrict__ x,
                          const float* __restrict__ w,
                          const float* __restrict__ b,
                          __hip_bfloat16* __restrict__ out) {
    int row = blockIdx.x, tid = threadIdx.x;
    const float* xr = x + (size_t)row * C_;
    float v0 = xr[tid], v1 = xr[tid + 256], v2 = xr[tid + 512];
    __shared__ float red[256];
    red[tid] = v0 + v1 + v2;
    __syncthreads();
    for (int s = 128; s; s >>= 1) {
        if (tid < s) red[tid] += red[tid + s];
        __syncthreads();
    }
    float mean = red[0] * (1.0f / C_);
    __syncthreads();
    float d0 = v0 - mean, d1 = v1 - mean, d2 = v2 - mean;
    red[tid] = d0 * d0 + d1 * d1 + d2 * d2;
    __syncthreads();
    for (int s = 128; s; s >>= 1) {
        if (tid < s) red[tid] += red[tid + s];
        __syncthreads();
    }
    float rstd = rsqrtf(red[0] * (1.0f / C_) + 1e-5f);
    __hip_bfloat16* o = out + (size_t)row * C_;
    o[tid]       = __float2bfloat16(d0 * rstd * w[tid]       + b[tid]);
    o[tid + 256] = __float2bfloat16(d1 * rstd * w[tid + 256] + b[tid + 256]);
    o[tid + 512] = __float2bfloat16(d2 * rstd * w[tid + 512] + b[tid + 512]);
}

// ---------------- transpose-convert W[K][N] f32 -> WT[N][K] bf16 ----------------
// generic, layered via blockIdx.z
__global__ void transpose_bf16_kernel(const float* __restrict__ W,
                                      __hip_bfloat16* __restrict__ WT,
                                      int K, int N,
                                      size_t sStride, size_t dStride) {
    int l = blockIdx.z;
    W += (size_t)l * sStride;
    WT += (size_t)l * dStride;
    __shared__ float tile[32][33];
    int n0 = blockIdx.x * 32, k0 = blockIdx.y * 32;
    int tx = threadIdx.x, ty = threadIdx.y;  // 32 x 8
    #pragma unroll
    for (int i = 0; i < 4; i++)
        tile[ty + 8 * i][tx] = W[(size_t)(k0 + ty + 8 * i) * N + n0 + tx];
    __syncthreads();
    #pragma unroll
    for (int i = 0; i < 4; i++)
        WT[(size_t)(n0 + ty + 8 * i) * K + k0 + tx] =
            __float2bfloat16(tile[tx][ty + 8 * i]);
}

// qkv: blockIdx.z = l*3 + which, dst packed [QKV][C] per layer
__global__ void transpose_qkv_kernel(const float* __restrict__ Wq,
                                     const float* __restrict__ Wk,
                                     const float* __restrict__ Wv,
                                     __hip_bfloat16* __restrict__ dst) {
    int z = blockIdx.z;
    int l = z / 3, which = z % 3;
    const float* W = (which == 0 ? Wq : which == 1 ? Wk : Wv) + (size_t)l * C_ * C_;
    __hip_bfloat16* WT = dst + (size_t)l * QKV_ * C_ + (size_t)which * C_ * C_;
    __shared__ float tile[32][33];
    int n0 = blockIdx.x * 32, k0 = blockIdx.y * 32;
    int tx = threadIdx.x, ty = threadIdx.y;
    #pragma unroll
    for (int i = 0; i < 4; i++)
        tile[ty + 8 * i][tx] = W[(size_t)(k0 + ty + 8 * i) * C_ + n0 + tx];
    __syncthreads();
    #pragma unroll
    for (int i = 0; i < 4; i++)
        WT[(size_t)(n0 + ty + 8 * i) * C_ + k0 + tx] =
            __float2bfloat16(tile[tx][ty + 8 * i]);
}

// ---------------- MFMA GEMM: 64x128 tile, BK=64, dbuf LDS + prefetch ----------
// A [M][K] bf16, WT [N][K] bf16. 1-D grid (M/64)*(N/128), XCD-swizzled.
// 4 waves, each owns a 32x64 quadrant (wr = w>>1 row-half, wc = w&1 col-half).
// LDS tiles XOR-swizzled (T2): global source chunk is pre-swizzled per rule #21
// (gload_lds dest must stay linear), reads apply the matching XOR.
template <bool BIAS, bool RES, bool RELU, bool OUTF, bool OUTB>
__global__ __launch_bounds__(256) void gemm64x128_kernel(
    const __hip_bfloat16* __restrict__ A,
    const __hip_bfloat16* __restrict__ WT,
    const float* __restrict__ bias,
    const float* __restrict__ res,
    float* __restrict__ outF,
    __hip_bfloat16* __restrict__ outB,
    int M, int N, int K, int nbx) {
    __shared__ __align__(16) short As[2 * 64 * 64];    // 2 x 8 KB
    __shared__ __align__(16) short Bs[2 * 128 * 64];   // 2 x 16 KB
    int tid = threadIdx.x;
    int lane = tid & 63;
    int w = tid >> 6;
    int l15 = lane & 15, l4 = lane >> 4;

    // XCD-aware bijective swizzle (all grids here are %8==0)
    int nwg = gridDim.x;
    int bid = blockIdx.x;
    int sbid = (bid & 7) * (nwg >> 3) + (bid >> 3);
    int bx = sbid % nbx, by = sbid / nbx;
    int row0 = by * 64, col0 = bx * 128;

    int wr = w >> 1, wc = w & 1;

    // staging: thread covers row rr (+32*i), source chunk XOR-swizzled by row&7
    int rr = tid >> 3;
    int cswz = (((tid & 7) ^ (rr & 7)) * 8);   // pre-swizzled global column (elems)
    const char* Ag = (const char*)A + ((size_t)(row0 + rr) * K + cswz) * 2;
    const char* Bg = (const char*)WT + ((size_t)(col0 + rr) * K + cswz) * 2;

    f32x4 acc[2][4] = {};
    int ktiles = K >> 6;

    auto stage = [&](int buf, int k0) {
        const char* Agk = Ag + (size_t)k0 * 2;
        const char* Bgk = Bg + (size_t)k0 * 2;
        #pragma unroll
        for (int i = 0; i < 2; i++)
            load_lds_16(Agk + (size_t)i * 32 * K * 2,
                        (char*)As + buf * 8192 + i * 4096 + w * 1024);
        #pragma unroll
        for (int i = 0; i < 4; i++)
            load_lds_16(Bgk + (size_t)i * 32 * K * 2,
                        (char*)Bs + buf * 16384 + i * 4096 + w * 1024);
    };

    stage(0, 0);
    __syncthreads();
    int cur = 0;
    int rxor = (l15 & 7) << 4;                 // read-side XOR (bytes)
    for (int t = 0; t < ktiles; ++t) {
        if (t + 1 < ktiles) stage(cur ^ 1, (t + 1) * 64);
        const char* Asb = (const char*)As + cur * 8192;
        const char* Bsb = (const char*)Bs + cur * 16384;
        #pragma unroll
        for (int kk = 0; kk < 2; kk++) {
            bf16x8 a[2], b[4];
            #pragma unroll
            for (int i = 0; i < 2; i++)
                a[i] = *(const bf16x8*)(Asb +
                        (wr * 32 + i * 16 + l15) * 128 + ((kk * 64 + l4 * 16) ^ rxor));
            #pragma unroll
            for (int j = 0; j < 4; j++)
                b[j] = *(const bf16x8*)(Bsb +
                        (wc * 64 + j * 16 + l15) * 128 + ((kk * 64 + l4 * 16) ^ rxor));
            #pragma unroll
            for (int i = 0; i < 2; i++)
                #pragma unroll
                for (int j = 0; j < 4; j++)
                    acc[i][j] = __builtin_amdgcn_mfma_f32_16x16x32_bf16(
                        a[i], b[j], acc[i][j], 0, 0, 0);
        }
        __syncthreads();   // drains prefetch vmem + guards buffer reuse
        cur ^= 1;
    }

    int rbase = l4 * 4;
    #pragma unroll
    for (int i = 0; i < 2; i++) {
        #pragma unroll
        for (int j = 0; j < 4; j++) {
            int col = col0 + wc * 64 + j * 16 + l15;
            float bv = BIAS ? bias[col] : 0.0f;
            #pragma unroll
            for (int r = 0; r < 4; r++) {
                int row = row0 + wr * 32 + i * 16 + rbase + r;
                size_t off = (size_t)row * N + col;
                float v = acc[i][j][r] + bv;
                if (RES) v += res[off];
                if (RELU) v = fmaxf(v, 0.0f);
                if (OUTF) outF[off] = v;
                if (OUTB) outB[off] = __float2bfloat16(v);
            }
        }
    }
}

// ---------------- flash attention: block = (b, h, 64 q rows), 4 waves ----------
__global__ __launch_bounds__(256) void attn_flash_kernel(
    const __hip_bfloat16* __restrict__ qkvb,
    __hip_bfloat16* __restrict__ attb) {
    int tid = threadIdx.x;
    int lane = tid & 63;
    int w = tid >> 6;
    int l15 = lane & 15;
    int l4 = lane >> 4;
    int qb0 = blockIdx.x * 64;
    int h = blockIdx.y;
    int b = blockIdx.z;

    __shared__ __align__(16) unsigned short Ks[64 * 64];
    __shared__ __align__(16) unsigned short Vt[64 * 64];
    __shared__ __align__(16) unsigned short Ps[4 * 16 * 64];

    const unsigned short* qkv = (const unsigned short*)qkvb;
    const unsigned short* Qg = qkv + (size_t)(b * T_ + qb0) * QKV_ + h * HS_;
    const unsigned short* Kg = qkv + (size_t)b * T_ * QKV_ + C_ + h * HS_;
    const unsigned short* Vg = qkv + (size_t)b * T_ * QKV_ + 2 * C_ + h * HS_;

    bf16x8 qfrag[2];
    {
        const short* qrow = (const short*)Qg + (size_t)(w * 16 + l15) * QKV_;
        qfrag[0] = *(const bf16x8*)(qrow + l4 * 8);
        qfrag[1] = *(const bf16x8*)(qrow + 32 + l4 * 8);
    }

    f32x4 o_acc[4] = {};
    float m_run[4], l_run[4];
    #pragma unroll
    for (int r = 0; r < 4; r++) { m_run[r] = -1e30f; l_run[r] = 0.0f; }

    unsigned short* Pw = Ps + w * 16 * 64;
    int nkb = blockIdx.x + 1;

    for (int kbi = 0; kbi < nkb; ++kbi) {
        int k0 = kbi * 64;
        __syncthreads();
        {
            int key = tid >> 3, ch = tid & 7;
            #pragma unroll
            for (int it = 0; it < 2; ++it) {
                int ky = key + it * 32;
                u16x8 kv = *(const u16x8*)(Kg + (size_t)(k0 + ky) * QKV_ + ch * 8);
                int byteoff = ky * 128 + ((ch * 16) ^ ((ky & 7) << 4));
                *(u16x8*)((char*)Ks + byteoff) = kv;

                u16x8 vv = *(const u16x8*)(Vg + (size_t)(k0 + ky) * QKV_ + ch * 8);
                #pragma unroll
                for (int e = 0; e < 8; ++e) {
                    int d = ch * 8 + e;
                    int slot = (d ^ (d >> 3)) & 7;
                    int boff = d * 128 + ((ky * 2) ^ (slot << 4));
                    *(unsigned short*)((char*)Vt + boff) = (unsigned short)vv[e];
                }
            }
        }
        __syncthreads();

        f32x4 s[4] = {};
        #pragma unroll
        for (int kk = 0; kk < 2; ++kk) {
            #pragma unroll
            for (int nt = 0; nt < 4; ++nt) {
                int key = nt * 16 + l15;
                int boff = key * 128 + (((l4 * 16) + kk * 64) ^ ((key & 7) << 4));
                bf16x8 kf = *(const bf16x8*)((char*)Ks + boff);
                s[nt] = __builtin_amdgcn_mfma_f32_16x16x32_bf16(qfrag[kk], kf, s[nt], 0, 0, 0);
            }
        }

        bool last = (kbi == nkb - 1);
        #pragma unroll
        for (int nt = 0; nt < 4; ++nt)
            #pragma unroll
            for (int r = 0; r < 4; ++r) {
                float v = s[nt][r] * 0.125f;
                if (last) {
                    int key = k0 + nt * 16 + l15;
                    int q = qb0 + w * 16 + l4 * 4 + r;
                    if (key > q) v = -1e30f;
                }
                s[nt][r] = v;
            }

        #pragma unroll
        for (int r = 0; r < 4; ++r) {
            float mx = fmaxf(fmaxf(s[0][r], s[1][r]), fmaxf(s[2][r], s[3][r]));
            #pragma unroll
            for (int o = 8; o; o >>= 1) mx = fmaxf(mx, __shfl_xor(mx, o));
            float mnew = fmaxf(m_run[r], mx);
            float alpha = __expf(m_run[r] - mnew);
            m_run[r] = mnew;
            float rs = 0.0f;
            #pragma unroll
            for (int nt = 0; nt < 4; ++nt) {
                float p = __expf(s[nt][r] - mnew);
                s[nt][r] = p;
                rs += p;
            }
            #pragma unroll
            for (int o = 8; o; o >>= 1) rs += __shfl_xor(rs, o);
            l_run[r] = l_run[r] * alpha + rs;
            #pragma unroll
            for (int nt = 0; nt < 4; ++nt) o_acc[nt][r] *= alpha;
        }

        #pragma unroll
        for (int nt = 0; nt < 4; ++nt)
            #pragma unroll
            for (int r = 0; r < 4; ++r) {
                int q = l4 * 4 + r;
                int col = nt * 16 + l15;
                int slot = (q ^ (q >> 3)) & 7;
                int boff = q * 128 + ((col * 2) ^ (slot << 4));
                *(unsigned short*)((char*)Pw + boff) = f2bbits(s[nt][r]);
            }

        #pragma unroll
        for (int kk = 0; kk < 2; ++kk) {
            int q = l15;
            int pslot = (q ^ (q >> 3)) & 7;
            int pboff = q * 128 + (((l4 * 16) + kk * 64) ^ (pslot << 4));
            bf16x8 pf = *(const bf16x8*)((char*)Pw + pboff);
            #pragma unroll
            for (int nt = 0; nt < 4; ++nt) {
                int d = nt * 16 + l15;
                int dslot = (d ^ (d >> 3)) & 7;
                int vboff = d * 128 + (((l4 * 16) + kk * 64) ^ (dslot << 4));
                bf16x8 vf = *(const bf16x8*)((char*)Vt + vboff);
                o_acc[nt] = __builtin_amdgcn_mfma_f32_16x16x32_bf16(pf, vf, o_acc[nt], 0, 0, 0);
            }
        }
    }

    unsigned short* Og = (unsigned short*)attb + (size_t)(b * T_ + qb0) * C_ + h * HS_;
    #pragma unroll
    for (int r = 0; r < 4; ++r) {
        float inv = 1.0f / l_run[r];
        #pragma unroll
        for (int nt = 0; nt < 4; ++nt) {
            float val = o_acc[nt][r] * inv;
            Og[(size_t)(w * 16 + l4 * 4 + r) * C_ + nt * 16 + l15] = f2bbits(val);
        }
    }
}

// ---------------- loss ----------------
__global__ void loss_rows_kernel(const float* __restrict__ logits,
                                 const int* __restrict__ targets,
                                 float* __restrict__ partials) {
    int row = blockIdx.x, tid = threadIdx.x;
    const float* lr = logits + (size_t)row * V_;
    __shared__ float red[256];
    float mx = -1e30f;
    for (int i = tid; i < V_; i += 256) mx = fmaxf(mx, lr[i]);
    red[tid] = mx;
    __syncthreads();
    for (int s = 128; s; s >>= 1) {
        if (tid < s) red[tid] = fmaxf(red[tid], red[tid + s]);
        __syncthreads();
    }
    mx = red[0];
    __syncthreads();
    float sum = 0.0f;
    for (int i = tid; i < V_; i += 256) sum += __expf(lr[i] - mx);
    red[tid] = sum;
    __syncthreads();
    for (int s = 128; s; s >>= 1) {
        if (tid < s) red[tid] += red[tid + s];
        __syncthreads();
    }
    if (tid == 0) {
        float lse = mx + __logf(red[0]);
        partials[row] = lse - lr[targets[row]];
    }
}

__global__ void loss_reduce_kernel(const float* __restrict__ partials,
                                   float* __restrict__ out) {
    int tid = threadIdx.x;
    float s = 0.0f;
    for (int i = tid; i < M_; i += 256) s += partials[i];
    __shared__ float red[256];
    red[tid] = s;
    __syncthreads();
    for (int st = 128; st; st >>= 1) {
        if (tid < st) red[tid] += red[tid + st];
        __syncthreads();
    }
    if (tid == 0) out[0] = red[0] * (1.0f / M_);
}

// ---------------- launch ----------------
extern "C" void kernel_launch(void* const* d_in, const int* in_sizes, int n_in,
                              void* d_out, int out_size, void* d_ws, size_t ws_size,
                              hipStream_t stream) {
    const int*   idx     = (const int*)d_in[0];
    const int*   targets = (const int*)d_in[1];
    const float* wte     = (const float*)d_in[2];
    const float* wpe     = (const float*)d_in[3];
    const float* lm_b    = (const float*)d_in[4];
    const float* ln1_w   = (const float*)d_in[5];
    const float* ln1_b   = (const float*)d_in[6];
    const float* Wq      = (const float*)d_in[7];
    const float* Wk      = (const float*)d_in[8];
    const float* Wv      = (const float*)d_in[9];
    const float* projW   = (const float*)d_in[10];
    const float* projb   = (const float*)d_in[11];
    const float* ln2_w   = (const float*)d_in[12];
    const float* ln2_b   = (const float*)d_in[13];
    const float* fc1W    = (const float*)d_in[14];
    const float* fc1b    = (const float*)d_in[15];
    const float* fc2W    = (const float*)d_in[16];
    const float* fc2b    = (const float*)d_in[17];
    const float* lnfw    = (const float*)d_in[18];
    const float* lnfb    = (const float*)d_in[19];

    char* ws = (char*)d_ws;
    size_t off = 0;
    float* x = (float*)(ws + off);                 off += (size_t)M_ * C_ * 4;
    __hip_bfloat16* h    = (__hip_bfloat16*)(ws + off); off += (size_t)M_ * C_ * 2;
    size_t qkv_off = off;
    __hip_bfloat16* qkvb = (__hip_bfloat16*)(ws + off); off += (size_t)M_ * QKV_ * 2;
    __hip_bfloat16* attb = (__hip_bfloat16*)(ws + off); off += (size_t)M_ * C_ * 2;
    __hip_bfloat16* fb   = (__hip_bfloat16*)(ws + qkv_off);  // aliases qkvb+attb
    __hip_bfloat16* wteB = (__hip_bfloat16*)(ws + off); off += (size_t)V_ * C_ * 2;
    float* partials = (float*)(ws + off);          off += (size_t)M_ * 4;

    // per-layer weight sizes (elements)
    const size_t QKV_SZ = (size_t)QKV_ * C_;
    const size_t WP_SZ  = (size_t)C_ * C_;
    const size_t F1_SZ  = (size_t)C_ * F_;
    const size_t F2_SZ  = (size_t)F_ * C_;
    size_t upfront_bytes = off + 2 * (size_t)L_ * (QKV_SZ + WP_SZ + F1_SZ + F2_SZ);
    bool upfront = ws_size >= upfront_bytes;
    int rep = upfront ? L_ : 1;

    __hip_bfloat16* qkvT0 = (__hip_bfloat16*)(ws + off); off += 2 * (size_t)rep * QKV_SZ;
    __hip_bfloat16* wpT0  = (__hip_bfloat16*)(ws + off); off += 2 * (size_t)rep * WP_SZ;
    __hip_bfloat16* wf1T0 = (__hip_bfloat16*)(ws + off); off += 2 * (size_t)rep * F1_SZ;
    __hip_bfloat16* wf2T0 = (__hip_bfloat16*)(ws + off); off += 2 * (size_t)rep * F2_SZ;

    float* logits = (float*)d_out;
    float* loss   = (float*)d_out + (size_t)M_ * V_;

    convert_bf16_kernel<<<(V_ * C_ + 255) / 256, 256, 0, stream>>>(wte, wteB, V_ * C_);
    embed_kernel<<<(M_ * C_) / 256, 256, 0, stream>>>(idx, wte, wpe, x);

    if (upfront) {
        transpose_qkv_kernel<<<dim3(C_ / 32, C_ / 32, 3 * L_), dim3(32, 8), 0, stream>>>(
            Wq, Wk, Wv, qkvT0);
        transpose_bf16_kernel<<<dim3(C_ / 32, C_ / 32, L_), dim3(32, 8), 0, stream>>>(
            projW, wpT0, C_, C_, WP_SZ, WP_SZ);
        transpose_bf16_kernel<<<dim3(F_ / 32, C_ / 32, L_), dim3(32, 8), 0, stream>>>(
            fc1W, wf1T0, C_, F_, F1_SZ, F1_SZ);
        transpose_bf16_kernel<<<dim3(C_ / 32, F_ / 32, L_), dim3(32, 8), 0, stream>>>(
            fc2W, wf2T0, F_, C_, F2_SZ, F2_SZ);
    }

    for (int l = 0; l < L_; l++) {
        __hip_bfloat16* qkvT = qkvT0 + (upfront ? (size_t)l * QKV_SZ : 0);
        __hip_bfloat16* wpT  = wpT0  + (upfront ? (size_t)l * WP_SZ : 0);
        __hip_bfloat16* wf1T = wf1T0 + (upfront ? (size_t)l * F1_SZ : 0);
        __hip_bfloat16* wf2T = wf2T0 + (upfront ? (size_t)l * F2_SZ : 0);

        ln_kernel<<<M_, 256, 0, stream>>>(x, ln1_w + l * C_, ln1_b + l * C_, h);

        if (!upfront)
            transpose_qkv_kernel<<<dim3(C_ / 32, C_ / 32, 3), dim3(32, 8), 0, stream>>>(
                Wq + (size_t)l * C_ * C_, Wk + (size_t)l * C_ * C_,
                Wv + (size_t)l * C_ * C_, qkvT);

        gemm64x128_kernel<false, false, false, false, true>
            <<<(M_ / 64) * (QKV_ / 128), 256, 0, stream>>>(
            h, qkvT, nullptr, nullptr, nullptr, qkvb, M_, QKV_, C_, QKV_ / 128);

        attn_flash_kernel<<<dim3(T_ / 64, H_, B_), 256, 0, stream>>>(qkvb, attb);

        if (!upfront)
            transpose_bf16_kernel<<<dim3(C_ / 32, C_ / 32, 1), dim3(32, 8), 0, stream>>>(
                projW + (size_t)l * C_ * C_, wpT, C_, C_, 0, 0);
        gemm64x128_kernel<true, true, false, true, false>
            <<<(M_ / 64) * (C_ / 128), 256, 0, stream>>>(
            attb, wpT, projb + l * C_, x, x, nullptr, M_, C_, C_, C_ / 128);

        ln_kernel<<<M_, 256, 0, stream>>>(x, ln2_w + l * C_, ln2_b + l * C_, h);

        if (!upfront)
            transpose_bf16_kernel<<<dim3(F_ / 32, C_ / 32, 1), dim3(32, 8), 0, stream>>>(
                fc1W + (size_t)l * C_ * F_, wf1T, C_, F_, 0, 0);
        gemm64x128_kernel<true, false, true, false, true>
            <<<(M_ / 64) * (F_ / 128), 256, 0, stream>>>(
            h, wf1T, fc1b + l * F_, nullptr, nullptr, fb, M_, F_, C_, F_ / 128);

        if (!upfront)
            transpose_bf16_kernel<<<dim3(C_ / 32, F_ / 32, 1), dim3(32, 8), 0, stream>>>(
                fc2W + (size_t)l * F_ * C_, wf2T, F_, C_, 0, 0);
        gemm64x128_kernel<true, true, false, true, false>
            <<<(M_ / 64) * (C_ / 128), 256, 0, stream>>>(
            fb, wf2T, fc2b + l * C_, x, x, nullptr, M_, C_, F_, C_ / 128);
    }

    ln_kernel<<<M_, 256, 0, stream>>>(x, lnfw, lnfb, h);
    gemm64x128_kernel<true, false, false, true, false>
        <<<(M_ / 64) * (V_ / 128), 256, 0, stream>>>(
        h, wteB, lm_b, nullptr, logits, nullptr, M_, V_, C_, V_ / 128);

    loss_rows_kernel<<<M_, 256, 0, stream>>>(logits, targets, partials);
    loss_reduce_kernel<<<1, 256, 0, stream>>>(partials, loss);
}

// Round 6
// 1154.165 us; speedup vs baseline: 6.3838x; 1.0142x over previous
//
#include <hip/hip_runtime.h>
#include <hip/hip_bf16.h>

typedef short bf16x8 __attribute__((ext_vector_type(8)));
typedef unsigned short u16x8 __attribute__((ext_vector_type(8)));
typedef float f32x4 __attribute__((ext_vector_type(4)));

#define B_ 4
#define T_ 1024
#define V_ 1024
#define C_ 768
#define H_ 12
#define HS_ 64
#define L_ 6
#define F_ 3072
#define M_ (B_ * T_)   // 4096 rows
#define QKV_ 2304      // fused q|k|v width

__device__ inline float b2f(unsigned short u) {
    return __uint_as_float(((unsigned int)u) << 16);
}
__device__ inline unsigned short f2bbits(float f) {
    __hip_bfloat16 h = __float2bfloat16(f);
    return *(unsigned short*)&h;
}
__device__ inline void load_lds_16(const void* g, void* l) {
    __builtin_amdgcn_global_load_lds(
        (const __attribute__((address_space(1))) unsigned int*)g,
        (__attribute__((address_space(3))) unsigned int*)l, 16, 0, 0);
}

// ---------------- elementwise / embedding ----------------
__global__ void convert_bf16_kernel(const float* __restrict__ in,
                                    __hip_bfloat16* __restrict__ out, int n) {
    int i = blockIdx.x * 256 + threadIdx.x;
    if (i < n) out[i] = __float2bfloat16(in[i]);
}

__global__ void embed_kernel(const int* __restrict__ idx,
                             const float* __restrict__ wte,
                             const float* __restrict__ wpe,
                             float* __restrict__ x) {
    int i = blockIdx.x * 256 + threadIdx.x;  // 0 .. M_*C_-1
    int row = i / C_;
    int c = i - row * C_;
    int t = row & (T_ - 1);
    x[i] = wte[(size_t)idx[row] * C_ + c] + wpe[(size_t)t * C_ + c];
}

// ---------------- layernorm (row of 768, block 256) ----------------
__global__ void ln_kernel(const float* __restrict__ x,
                          const float* __restrict__ w,
                          const float* __restrict__ b,
                          __hip_bfloat16* __restrict__ out) {
    int row = blockIdx.x, tid = threadIdx.x;
    const float* xr = x + (size_t)row * C_;
    float v0 = xr[tid], v1 = xr[tid + 256], v2 = xr[tid + 512];
    __shared__ float red[256];
    red[tid] = v0 + v1 + v2;
    __syncthreads();
    for (int s = 128; s; s >>= 1) {
        if (tid < s) red[tid] += red[tid + s];
        __syncthreads();
    }
    float mean = red[0] * (1.0f / C_);
    __syncthreads();
    float d0 = v0 - mean, d1 = v1 - mean, d2 = v2 - mean;
    red[tid] = d0 * d0 + d1 * d1 + d2 * d2;
    __syncthreads();
    for (int s = 128; s; s >>= 1) {
        if (tid < s) red[tid] += red[tid + s];
        __syncthreads();
    }
    float rstd = rsqrtf(red[0] * (1.0f / C_) + 1e-5f);
    __hip_bfloat16* o = out + (size_t)row * C_;
    o[tid]       = __float2bfloat16(d0 * rstd * w[tid]       + b[tid]);
    o[tid + 256] = __float2bfloat16(d1 * rstd * w[tid + 256] + b[tid + 256]);
    o[tid + 512] = __float2bfloat16(d2 * rstd * w[tid + 512] + b[tid + 512]);
}

// ---------------- transpose-convert W[K][N] f32 -> WT[N][K] bf16 ----------------
__global__ void transpose_bf16_kernel(const float* __restrict__ W,
                                      __hip_bfloat16* __restrict__ WT,
                                      int K, int N,
                                      size_t sStride, size_t dStride) {
    int l = blockIdx.z;
    W += (size_t)l * sStride;
    WT += (size_t)l * dStride;
    __shared__ float tile[32][33];
    int n0 = blockIdx.x * 32, k0 = blockIdx.y * 32;
    int tx = threadIdx.x, ty = threadIdx.y;  // 32 x 8
    #pragma unroll
    for (int i = 0; i < 4; i++)
        tile[ty + 8 * i][tx] = W[(size_t)(k0 + ty + 8 * i) * N + n0 + tx];
    __syncthreads();
    #pragma unroll
    for (int i = 0; i < 4; i++)
        WT[(size_t)(n0 + ty + 8 * i) * K + k0 + tx] =
            __float2bfloat16(tile[tx][ty + 8 * i]);
}

// qkv: blockIdx.z = l*3 + which, dst packed [QKV][C] per layer
__global__ void transpose_qkv_kernel(const float* __restrict__ Wq,
                                     const float* __restrict__ Wk,
                                     const float* __restrict__ Wv,
                                     __hip_bfloat16* __restrict__ dst) {
    int z = blockIdx.z;
    int l = z / 3, which = z % 3;
    const float* W = (which == 0 ? Wq : which == 1 ? Wk : Wv) + (size_t)l * C_ * C_;
    __hip_bfloat16* WT = dst + (size_t)l * QKV_ * C_ + (size_t)which * C_ * C_;
    __shared__ float tile[32][33];
    int n0 = blockIdx.x * 32, k0 = blockIdx.y * 32;
    int tx = threadIdx.x, ty = threadIdx.y;
    #pragma unroll
    for (int i = 0; i < 4; i++)
        tile[ty + 8 * i][tx] = W[(size_t)(k0 + ty + 8 * i) * C_ + n0 + tx];
    __syncthreads();
    #pragma unroll
    for (int i = 0; i < 4; i++)
        WT[(size_t)(n0 + ty + 8 * i) * C_ + k0 + tx] =
            __float2bfloat16(tile[tx][ty + 8 * i]);
}

// ---------------- MFMA GEMM: 64x128 tile, BK=64, dbuf LDS + prefetch ----------
template <bool BIAS, bool RES, bool RELU, bool OUTF, bool OUTB>
__global__ __launch_bounds__(256) void gemm64x128_kernel(
    const __hip_bfloat16* __restrict__ A,
    const __hip_bfloat16* __restrict__ WT,
    const float* __restrict__ bias,
    const float* __restrict__ res,
    float* __restrict__ outF,
    __hip_bfloat16* __restrict__ outB,
    int M, int N, int K, int nbx) {
    __shared__ __align__(16) short As[2 * 64 * 64];    // 2 x 8 KB
    __shared__ __align__(16) short Bs[2 * 128 * 64];   // 2 x 16 KB
    int tid = threadIdx.x;
    int lane = tid & 63;
    int w = tid >> 6;
    int l15 = lane & 15, l4 = lane >> 4;

    int nwg = gridDim.x;
    int bid = blockIdx.x;
    int sbid = (bid & 7) * (nwg >> 3) + (bid >> 3);
    int bx = sbid % nbx, by = sbid / nbx;
    int row0 = by * 64, col0 = bx * 128;

    int wr = w >> 1, wc = w & 1;

    int rr = tid >> 3;
    int cswz = (((tid & 7) ^ (rr & 7)) * 8);   // pre-swizzled global column (elems)
    const char* Ag = (const char*)A + ((size_t)(row0 + rr) * K + cswz) * 2;
    const char* Bg = (const char*)WT + ((size_t)(col0 + rr) * K + cswz) * 2;

    f32x4 acc[2][4] = {};
    int ktiles = K >> 6;

    auto stage = [&](int buf, int k0) {
        const char* Agk = Ag + (size_t)k0 * 2;
        const char* Bgk = Bg + (size_t)k0 * 2;
        #pragma unroll
        for (int i = 0; i < 2; i++)
            load_lds_16(Agk + (size_t)i * 32 * K * 2,
                        (char*)As + buf * 8192 + i * 4096 + w * 1024);
        #pragma unroll
        for (int i = 0; i < 4; i++)
            load_lds_16(Bgk + (size_t)i * 32 * K * 2,
                        (char*)Bs + buf * 16384 + i * 4096 + w * 1024);
    };

    stage(0, 0);
    __syncthreads();
    int cur = 0;
    int rxor = (l15 & 7) << 4;                 // read-side XOR (bytes)
    for (int t = 0; t < ktiles; ++t) {
        if (t + 1 < ktiles) stage(cur ^ 1, (t + 1) * 64);
        const char* Asb = (const char*)As + cur * 8192;
        const char* Bsb = (const char*)Bs + cur * 16384;
        #pragma unroll
        for (int kk = 0; kk < 2; kk++) {
            bf16x8 a[2], b[4];
            #pragma unroll
            for (int i = 0; i < 2; i++)
                a[i] = *(const bf16x8*)(Asb +
                        (wr * 32 + i * 16 + l15) * 128 + ((kk * 64 + l4 * 16) ^ rxor));
            #pragma unroll
            for (int j = 0; j < 4; j++)
                b[j] = *(const bf16x8*)(Bsb +
                        (wc * 64 + j * 16 + l15) * 128 + ((kk * 64 + l4 * 16) ^ rxor));
            #pragma unroll
            for (int i = 0; i < 2; i++)
                #pragma unroll
                for (int j = 0; j < 4; j++)
                    acc[i][j] = __builtin_amdgcn_mfma_f32_16x16x32_bf16(
                        a[i], b[j], acc[i][j], 0, 0, 0);
        }
        __syncthreads();
        cur ^= 1;
    }

    int rbase = l4 * 4;
    #pragma unroll
    for (int i = 0; i < 2; i++) {
        #pragma unroll
        for (int j = 0; j < 4; j++) {
            int col = col0 + wc * 64 + j * 16 + l15;
            float bv = BIAS ? bias[col] : 0.0f;
            #pragma unroll
            for (int r = 0; r < 4; r++) {
                int row = row0 + wr * 32 + i * 16 + rbase + r;
                size_t off = (size_t)row * N + col;
                float v = acc[i][j][r] + bv;
                if (RES) v += res[off];
                if (RELU) v = fmaxf(v, 0.0f);
                if (OUTF) outF[off] = v;
                if (OUTB) outB[off] = __float2bfloat16(v);
            }
        }
    }
}

// ---------------- flash attention: QBLK=128, 4 waves x 32 q-rows --------------
// 1-D grid of 384. XCD-affinity mapping: all 8 q-chunks of one (b,h) land on
// the same XCD (K/V stays in that XCD's 4MB L2). Longest chunks dispatch first.
__global__ __launch_bounds__(256) void attn_flash_kernel(
    const __hip_bfloat16* __restrict__ qkvb,
    __hip_bfloat16* __restrict__ attb) {
    int tid = threadIdx.x;
    int lane = tid & 63;
    int w = tid >> 6;
    int l15 = lane & 15;
    int l4 = lane >> 4;

    int bid = blockIdx.x;            // 0..383
    int xcd = bid & 7, i = bid >> 3; // i 0..47
    int qc = 7 - (i / 6);            // descending: long blocks first
    int bh = (i % 6) * 8 + xcd;      // all qc of this bh share an XCD
    int b = bh / H_, h = bh % H_;
    int qb0 = qc * 128;

    __shared__ __align__(16) unsigned short Ks[64 * 64];      // swizzled [key][d]
    __shared__ __align__(16) unsigned short Vt[64 * 64];      // swizzled [d][key]
    __shared__ __align__(16) unsigned short Ps[4 * 32 * 64];  // per-wave [q][key]

    const unsigned short* qkv = (const unsigned short*)qkvb;
    const unsigned short* Qg = qkv + (size_t)(b * T_ + qb0) * QKV_ + h * HS_;
    const unsigned short* Kg = qkv + (size_t)b * T_ * QKV_ + C_ + h * HS_;
    const unsigned short* Vg = qkv + (size_t)b * T_ * QKV_ + 2 * C_ + h * HS_;

    // Q fragments: wave w owns q rows w*32 .. w*32+31 (2 tiles of 16)
    bf16x8 qfrag[2][2];
    #pragma unroll
    for (int qt = 0; qt < 2; qt++) {
        const short* qrow = (const short*)Qg + (size_t)(w * 32 + qt * 16 + l15) * QKV_;
        qfrag[qt][0] = *(const bf16x8*)(qrow + l4 * 8);
        qfrag[qt][1] = *(const bf16x8*)(qrow + 32 + l4 * 8);
    }

    f32x4 o_acc[2][4] = {};
    float m_run[2][4], l_run[2][4];
    #pragma unroll
    for (int qt = 0; qt < 2; qt++)
        #pragma unroll
        for (int r = 0; r < 4; r++) { m_run[qt][r] = -1e30f; l_run[qt][r] = 0.0f; }

    unsigned short* Pw = Ps + w * 32 * 64;
    int nkb = (qc + 1) * 2;

    for (int kbi = 0; kbi < nkb; ++kbi) {
        int k0 = kbi * 64;
        __syncthreads();
        // ---- stage K (swizzled) and V (transposed+swizzled) ----
        {
            int key = tid >> 3, ch = tid & 7;
            #pragma unroll
            for (int it = 0; it < 2; ++it) {
                int ky = key + it * 32;
                u16x8 kv = *(const u16x8*)(Kg + (size_t)(k0 + ky) * QKV_ + ch * 8);
                int byteoff = ky * 128 + ((ch * 16) ^ ((ky & 7) << 4));
                *(u16x8*)((char*)Ks + byteoff) = kv;

                u16x8 vv = *(const u16x8*)(Vg + (size_t)(k0 + ky) * QKV_ + ch * 8);
                #pragma unroll
                for (int e = 0; e < 8; ++e) {
                    int d = ch * 8 + e;
                    int slot = (d ^ (d >> 3)) & 7;
                    int boff = d * 128 + ((ky * 2) ^ (slot << 4));
                    *(unsigned short*)((char*)Vt + boff) = (unsigned short)vv[e];
                }
            }
        }
        __syncthreads();

        // ---- S = Q K^T (K fragments shared across the 2 q-tiles) ----
        f32x4 s[2][4] = {};
        #pragma unroll
        for (int kk = 0; kk < 2; ++kk) {
            #pragma unroll
            for (int nt = 0; nt < 4; ++nt) {
                int key = nt * 16 + l15;
                int boff = key * 128 + (((l4 * 16) + kk * 64) ^ ((key & 7) << 4));
                bf16x8 kf = *(const bf16x8*)((char*)Ks + boff);
                #pragma unroll
                for (int qt = 0; qt < 2; ++qt)
                    s[qt][nt] = __builtin_amdgcn_mfma_f32_16x16x32_bf16(
                        qfrag[qt][kk], kf, s[qt][nt], 0, 0, 0);
            }
        }

        // ---- scale + causal mask (only the <=2 diagonal tiles) ----
        bool maskt = (kbi >= 2 * qc);
        #pragma unroll
        for (int qt = 0; qt < 2; ++qt)
            #pragma unroll
            for (int nt = 0; nt < 4; ++nt)
                #pragma unroll
                for (int r = 0; r < 4; ++r) {
                    float v = s[qt][nt][r] * 0.125f;
                    if (maskt) {
                        int key = k0 + nt * 16 + l15;
                        int q = qb0 + w * 32 + qt * 16 + l4 * 4 + r;
                        if (key > q) v = -1e30f;
                    }
                    s[qt][nt][r] = v;
                }

        // ---- online softmax ----
        #pragma unroll
        for (int qt = 0; qt < 2; ++qt)
            #pragma unroll
            for (int r = 0; r < 4; ++r) {
                float mx = fmaxf(fmaxf(s[qt][0][r], s[qt][1][r]),
                                 fmaxf(s[qt][2][r], s[qt][3][r]));
                #pragma unroll
                for (int o = 8; o; o >>= 1) mx = fmaxf(mx, __shfl_xor(mx, o));
                float mnew = fmaxf(m_run[qt][r], mx);
                float alpha = __expf(m_run[qt][r] - mnew);
                m_run[qt][r] = mnew;
                float rs = 0.0f;
                #pragma unroll
                for (int nt = 0; nt < 4; ++nt) {
                    float p = __expf(s[qt][nt][r] - mnew);
                    s[qt][nt][r] = p;
                    rs += p;
                }
                #pragma unroll
                for (int o = 8; o; o >>= 1) rs += __shfl_xor(rs, o);
                l_run[qt][r] = l_run[qt][r] * alpha + rs;
                #pragma unroll
                for (int nt = 0; nt < 4; ++nt) o_acc[qt][nt][r] *= alpha;
            }

        // ---- write P to per-wave LDS (C layout -> swizzled [q][key]) ----
        #pragma unroll
        for (int qt = 0; qt < 2; ++qt)
            #pragma unroll
            for (int nt = 0; nt < 4; ++nt)
                #pragma unroll
                for (int r = 0; r < 4; ++r) {
                    int q = qt * 16 + l4 * 4 + r;
                    int col = nt * 16 + l15;
                    int boff = q * 128 + ((col * 2) ^ ((q & 7) << 4));
                    *(unsigned short*)((char*)Pw + boff) = f2bbits(s[qt][nt][r]);
                }

        // ---- O += P V (V fragments shared across the 2 q-tiles) ----
        #pragma unroll
        for (int kk = 0; kk < 2; ++kk) {
            bf16x8 pf[2];
            #pragma unroll
            for (int qt = 0; qt < 2; ++qt) {
                int q = qt * 16 + l15;
                int pboff = q * 128 + (((l4 * 16) + kk * 64) ^ ((q & 7) << 4));
                pf[qt] = *(const bf16x8*)((char*)Pw + pboff);
            }
            #pragma unroll
            for (int nt = 0; nt < 4; ++nt) {
                int d = nt * 16 + l15;
                int dslot = (d ^ (d >> 3)) & 7;
                int vboff = d * 128 + (((l4 * 16) + kk * 64) ^ (dslot << 4));
                bf16x8 vf = *(const bf16x8*)((char*)Vt + vboff);
                #pragma unroll
                for (int qt = 0; qt < 2; ++qt)
                    o_acc[qt][nt] = __builtin_amdgcn_mfma_f32_16x16x32_bf16(
                        pf[qt], vf, o_acc[qt][nt], 0, 0, 0);
            }
        }
    }

    // ---- epilogue ----
    unsigned short* Og = (unsigned short*)attb + (size_t)(b * T_ + qb0) * C_ + h * HS_;
    #pragma unroll
    for (int qt = 0; qt < 2; ++qt)
        #pragma unroll
        for (int r = 0; r < 4; ++r) {
            float inv = 1.0f / l_run[qt][r];
            #pragma unroll
            for (int nt = 0; nt < 4; ++nt) {
                float val = o_acc[qt][nt][r] * inv;
                Og[(size_t)(w * 32 + qt * 16 + l4 * 4 + r) * C_ + nt * 16 + l15] =
                    f2bbits(val);
            }
        }
}

// ---------------- loss ----------------
__global__ void loss_rows_kernel(const float* __restrict__ logits,
                                 const int* __restrict__ targets,
                                 float* __restrict__ partials) {
    int row = blockIdx.x, tid = threadIdx.x;
    const float* lr = logits + (size_t)row * V_;
    __shared__ float red[256];
    float mx = -1e30f;
    for (int i = tid; i < V_; i += 256) mx = fmaxf(mx, lr[i]);
    red[tid] = mx;
    __syncthreads();
    for (int s = 128; s; s >>= 1) {
        if (tid < s) red[tid] = fmaxf(red[tid], red[tid + s]);
        __syncthreads();
    }
    mx = red[0];
    __syncthreads();
    float sum = 0.0f;
    for (int i = tid; i < V_; i += 256) sum += __expf(lr[i] - mx);
    red[tid] = sum;
    __syncthreads();
    for (int s = 128; s; s >>= 1) {
        if (tid < s) red[tid] += red[tid + s];
        __syncthreads();
    }
    if (tid == 0) {
        float lse = mx + __logf(red[0]);
        partials[row] = lse - lr[targets[row]];
    }
}

__global__ void loss_reduce_kernel(const float* __restrict__ partials,
                                   float* __restrict__ out) {
    int tid = threadIdx.x;
    float s = 0.0f;
    for (int i = tid; i < M_; i += 256) s += partials[i];
    __shared__ float red[256];
    red[tid] = s;
    __syncthreads();
    for (int st = 128; st; st >>= 1) {
        if (tid < st) red[tid] += red[tid + st];
        __syncthreads();
    }
    if (tid == 0) out[0] = red[0] * (1.0f / M_);
}

// ---------------- launch ----------------
extern "C" void kernel_launch(void* const* d_in, const int* in_sizes, int n_in,
                              void* d_out, int out_size, void* d_ws, size_t ws_size,
                              hipStream_t stream) {
    const int*   idx     = (const int*)d_in[0];
    const int*   targets = (const int*)d_in[1];
    const float* wte     = (const float*)d_in[2];
    const float* wpe     = (const float*)d_in[3];
    const float* lm_b    = (const float*)d_in[4];
    const float* ln1_w   = (const float*)d_in[5];
    const float* ln1_b   = (const float*)d_in[6];
    const float* Wq      = (const float*)d_in[7];
    const float* Wk      = (const float*)d_in[8];
    const float* Wv      = (const float*)d_in[9];
    const float* projW   = (const float*)d_in[10];
    const float* projb   = (const float*)d_in[11];
    const float* ln2_w   = (const float*)d_in[12];
    const float* ln2_b   = (const float*)d_in[13];
    const float* fc1W    = (const float*)d_in[14];
    const float* fc1b    = (const float*)d_in[15];
    const float* fc2W    = (const float*)d_in[16];
    const float* fc2b    = (const float*)d_in[17];
    const float* lnfw    = (const float*)d_in[18];
    const float* lnfb    = (const float*)d_in[19];

    char* ws = (char*)d_ws;
    size_t off = 0;
    float* x = (float*)(ws + off);                 off += (size_t)M_ * C_ * 4;
    __hip_bfloat16* h    = (__hip_bfloat16*)(ws + off); off += (size_t)M_ * C_ * 2;
    size_t qkv_off = off;
    __hip_bfloat16* qkvb = (__hip_bfloat16*)(ws + off); off += (size_t)M_ * QKV_ * 2;
    __hip_bfloat16* attb = (__hip_bfloat16*)(ws + off); off += (size_t)M_ * C_ * 2;
    __hip_bfloat16* fb   = (__hip_bfloat16*)(ws + qkv_off);  // aliases qkvb+attb
    __hip_bfloat16* wteB = (__hip_bfloat16*)(ws + off); off += (size_t)V_ * C_ * 2;
    float* partials = (float*)(ws + off);          off += (size_t)M_ * 4;

    const size_t QKV_SZ = (size_t)QKV_ * C_;
    const size_t WP_SZ  = (size_t)C_ * C_;
    const size_t F1_SZ  = (size_t)C_ * F_;
    const size_t F2_SZ  = (size_t)F_ * C_;
    size_t upfront_bytes = off + 2 * (size_t)L_ * (QKV_SZ + WP_SZ + F1_SZ + F2_SZ);
    bool upfront = ws_size >= upfront_bytes;
    int rep = upfront ? L_ : 1;

    __hip_bfloat16* qkvT0 = (__hip_bfloat16*)(ws + off); off += 2 * (size_t)rep * QKV_SZ;
    __hip_bfloat16* wpT0  = (__hip_bfloat16*)(ws + off); off += 2 * (size_t)rep * WP_SZ;
    __hip_bfloat16* wf1T0 = (__hip_bfloat16*)(ws + off); off += 2 * (size_t)rep * F1_SZ;
    __hip_bfloat16* wf2T0 = (__hip_bfloat16*)(ws + off); off += 2 * (size_t)rep * F2_SZ;

    float* logits = (float*)d_out;
    float* loss   = (float*)d_out + (size_t)M_ * V_;

    convert_bf16_kernel<<<(V_ * C_ + 255) / 256, 256, 0, stream>>>(wte, wteB, V_ * C_);
    embed_kernel<<<(M_ * C_) / 256, 256, 0, stream>>>(idx, wte, wpe, x);

    if (upfront) {
        transpose_qkv_kernel<<<dim3(C_ / 32, C_ / 32, 3 * L_), dim3(32, 8), 0, stream>>>(
            Wq, Wk, Wv, qkvT0);
        transpose_bf16_kernel<<<dim3(C_ / 32, C_ / 32, L_), dim3(32, 8), 0, stream>>>(
            projW, wpT0, C_, C_, WP_SZ, WP_SZ);
        transpose_bf16_kernel<<<dim3(F_ / 32, C_ / 32, L_), dim3(32, 8), 0, stream>>>(
            fc1W, wf1T0, C_, F_, F1_SZ, F1_SZ);
        transpose_bf16_kernel<<<dim3(C_ / 32, F_ / 32, L_), dim3(32, 8), 0, stream>>>(
            fc2W, wf2T0, F_, C_, F2_SZ, F2_SZ);
    }

    for (int l = 0; l < L_; l++) {
        __hip_bfloat16* qkvT = qkvT0 + (upfront ? (size_t)l * QKV_SZ : 0);
        __hip_bfloat16* wpT  = wpT0  + (upfront ? (size_t)l * WP_SZ : 0);
        __hip_bfloat16* wf1T = wf1T0 + (upfront ? (size_t)l * F1_SZ : 0);
        __hip_bfloat16* wf2T = wf2T0 + (upfront ? (size_t)l * F2_SZ : 0);

        ln_kernel<<<M_, 256, 0, stream>>>(x, ln1_w + l * C_, ln1_b + l * C_, h);

        if (!upfront)
            transpose_qkv_kernel<<<dim3(C_ / 32, C_ / 32, 3), dim3(32, 8), 0, stream>>>(
                Wq + (size_t)l * C_ * C_, Wk + (size_t)l * C_ * C_,
                Wv + (size_t)l * C_ * C_, qkvT);

        gemm64x128_kernel<false, false, false, false, true>
            <<<(M_ / 64) * (QKV_ / 128), 256, 0, stream>>>(
            h, qkvT, nullptr, nullptr, nullptr, qkvb, M_, QKV_, C_, QKV_ / 128);

        attn_flash_kernel<<<B_ * H_ * (T_ / 128), 256, 0, stream>>>(qkvb, attb);

        if (!upfront)
            transpose_bf16_kernel<<<dim3(C_ / 32, C_ / 32, 1), dim3(32, 8), 0, stream>>>(
                projW + (size_t)l * C_ * C_, wpT, C_, C_, 0, 0);
        gemm64x128_kernel<true, true, false, true, false>
            <<<(M_ / 64) * (C_ / 128), 256, 0, stream>>>(
            attb, wpT, projb + l * C_, x, x, nullptr, M_, C_, C_, C_ / 128);

        ln_kernel<<<M_, 256, 0, stream>>>(x, ln2_w + l * C_, ln2_b + l * C_, h);

        if (!upfront)
            transpose_bf16_kernel<<<dim3(F_ / 32, C_ / 32, 1), dim3(32, 8), 0, stream>>>(
                fc1W + (size_t)l * C_ * F_, wf1T, C_, F_, 0, 0);
        gemm64x128_kernel<true, false, true, false, true>
            <<<(M_ / 64) * (F_ / 128), 256, 0, stream>>>(
            h, wf1T, fc1b + l * F_, nullptr, nullptr, fb, M_, F_, C_, F_ / 128);

        if (!upfront)
            transpose_bf16_kernel<<<dim3(C_ / 32, F_ / 32, 1), dim3(32, 8), 0, stream>>>(
                fc2W + (size_t)l * F_ * C_, wf2T, F_, C_, 0, 0);
        gemm64x128_kernel<true, true, false, true, false>
            <<<(M_ / 64) * (C_ / 128), 256, 0, stream>>>(
            fb, wf2T, fc2b + l * C_, x, x, nullptr, M_, C_, F_, C_ / 128);
    }

    ln_kernel<<<M_, 256, 0, stream>>>(x, lnfw, lnfb, h);
    gemm64x128_kernel<true, false, false, true, false>
        <<<(M_ / 64) * (V_ / 128), 256, 0, stream>>>(
        h, wteB, lm_b, nullptr, logits, nullptr, M_, V_, C_, V_ / 128);

    loss_rows_kernel<<<M_, 256, 0, stream>>>(logits, targets, partials);
    loss_reduce_kernel<<<1, 256, 0, stream>>>(partials, loss);
}

// Round 7
// 1102.050 us; speedup vs baseline: 6.6857x; 1.0473x over previous
//
#include <hip/hip_runtime.h>
#include <hip/hip_bf16.h>

typedef short bf16x8 __attribute__((ext_vector_type(8)));
typedef unsigned short u16x8 __attribute__((ext_vector_type(8)));
typedef float f32x4 __attribute__((ext_vector_type(4)));

#define B_ 4
#define T_ 1024
#define V_ 1024
#define C_ 768
#define H_ 12
#define HS_ 64
#define L_ 6
#define F_ 3072
#define M_ (B_ * T_)   // 4096 rows
#define QKV_ 2304      // fused q|k|v width

__device__ inline float b2f(unsigned short u) {
    return __uint_as_float(((unsigned int)u) << 16);
}
__device__ inline unsigned short f2bbits(float f) {
    __hip_bfloat16 h = __float2bfloat16(f);
    return *(unsigned short*)&h;
}
__device__ inline void load_lds_16(const void* g, void* l) {
    __builtin_amdgcn_global_load_lds(
        (const __attribute__((address_space(1))) unsigned int*)g,
        (__attribute__((address_space(3))) unsigned int*)l, 16, 0, 0);
}

// ---------------- elementwise / embedding ----------------
__global__ void convert_bf16_kernel(const float* __restrict__ in,
                                    __hip_bfloat16* __restrict__ out, int n) {
    int i = blockIdx.x * 256 + threadIdx.x;
    if (i < n) out[i] = __float2bfloat16(in[i]);
}

__global__ void embed_kernel(const int* __restrict__ idx,
                             const float* __restrict__ wte,
                             const float* __restrict__ wpe,
                             float* __restrict__ x) {
    int i = blockIdx.x * 256 + threadIdx.x;  // 0 .. M_*C_-1
    int row = i / C_;
    int c = i - row * C_;
    int t = row & (T_ - 1);
    x[i] = wte[(size_t)idx[row] * C_ + c] + wpe[(size_t)t * C_ + c];
}

// ---------------- layernorm (row of 768, block 256) ----------------
__global__ void ln_kernel(const float* __restrict__ x,
                          const float* __restrict__ w,
                          const float* __restrict__ b,
                          __hip_bfloat16* __restrict__ out) {
    int row = blockIdx.x, tid = threadIdx.x;
    const float* xr = x + (size_t)row * C_;
    float v0 = xr[tid], v1 = xr[tid + 256], v2 = xr[tid + 512];
    __shared__ float red[256];
    red[tid] = v0 + v1 + v2;
    __syncthreads();
    for (int s = 128; s; s >>= 1) {
        if (tid < s) red[tid] += red[tid + s];
        __syncthreads();
    }
    float mean = red[0] * (1.0f / C_);
    __syncthreads();
    float d0 = v0 - mean, d1 = v1 - mean, d2 = v2 - mean;
    red[tid] = d0 * d0 + d1 * d1 + d2 * d2;
    __syncthreads();
    for (int s = 128; s; s >>= 1) {
        if (tid < s) red[tid] += red[tid + s];
        __syncthreads();
    }
    float rstd = rsqrtf(red[0] * (1.0f / C_) + 1e-5f);
    __hip_bfloat16* o = out + (size_t)row * C_;
    o[tid]       = __float2bfloat16(d0 * rstd * w[tid]       + b[tid]);
    o[tid + 256] = __float2bfloat16(d1 * rstd * w[tid + 256] + b[tid + 256]);
    o[tid + 512] = __float2bfloat16(d2 * rstd * w[tid + 512] + b[tid + 512]);
}

// ---------------- transpose-convert W[K][N] f32 -> WT[N][K] bf16 ----------------
__global__ void transpose_bf16_kernel(const float* __restrict__ W,
                                      __hip_bfloat16* __restrict__ WT,
                                      int K, int N,
                                      size_t sStride, size_t dStride) {
    int l = blockIdx.z;
    W += (size_t)l * sStride;
    WT += (size_t)l * dStride;
    __shared__ float tile[32][33];
    int n0 = blockIdx.x * 32, k0 = blockIdx.y * 32;
    int tx = threadIdx.x, ty = threadIdx.y;  // 32 x 8
    #pragma unroll
    for (int i = 0; i < 4; i++)
        tile[ty + 8 * i][tx] = W[(size_t)(k0 + ty + 8 * i) * N + n0 + tx];
    __syncthreads();
    #pragma unroll
    for (int i = 0; i < 4; i++)
        WT[(size_t)(n0 + ty + 8 * i) * K + k0 + tx] =
            __float2bfloat16(tile[tx][ty + 8 * i]);
}

// qkv: blockIdx.z = l*3 + which, dst packed [QKV][C] per layer
__global__ void transpose_qkv_kernel(const float* __restrict__ Wq,
                                     const float* __restrict__ Wk,
                                     const float* __restrict__ Wv,
                                     __hip_bfloat16* __restrict__ dst) {
    int z = blockIdx.z;
    int l = z / 3, which = z % 3;
    const float* W = (which == 0 ? Wq : which == 1 ? Wk : Wv) + (size_t)l * C_ * C_;
    __hip_bfloat16* WT = dst + (size_t)l * QKV_ * C_ + (size_t)which * C_ * C_;
    __shared__ float tile[32][33];
    int n0 = blockIdx.x * 32, k0 = blockIdx.y * 32;
    int tx = threadIdx.x, ty = threadIdx.y;
    #pragma unroll
    for (int i = 0; i < 4; i++)
        tile[ty + 8 * i][tx] = W[(size_t)(k0 + ty + 8 * i) * C_ + n0 + tx];
    __syncthreads();
    #pragma unroll
    for (int i = 0; i < 4; i++)
        WT[(size_t)(n0 + ty + 8 * i) * C_ + k0 + tx] =
            __float2bfloat16(tile[tx][ty + 8 * i]);
}

// ---------------- MFMA GEMM: 64x128 tile, BK=64, dbuf LDS + prefetch ----------
template <bool BIAS, bool RES, bool RELU, bool OUTF, bool OUTB>
__global__ __launch_bounds__(256) void gemm64x128_kernel(
    const __hip_bfloat16* __restrict__ A,
    const __hip_bfloat16* __restrict__ WT,
    const float* __restrict__ bias,
    const float* __restrict__ res,
    float* __restrict__ outF,
    __hip_bfloat16* __restrict__ outB,
    int M, int N, int K, int nbx) {
    __shared__ __align__(16) short As[2 * 64 * 64];    // 2 x 8 KB
    __shared__ __align__(16) short Bs[2 * 128 * 64];   // 2 x 16 KB
    int tid = threadIdx.x;
    int lane = tid & 63;
    int w = tid >> 6;
    int l15 = lane & 15, l4 = lane >> 4;

    int nwg = gridDim.x;
    int bid = blockIdx.x;
    int sbid = (bid & 7) * (nwg >> 3) + (bid >> 3);
    int bx = sbid % nbx, by = sbid / nbx;
    int row0 = by * 64, col0 = bx * 128;

    int wr = w >> 1, wc = w & 1;

    int rr = tid >> 3;
    int cswz = (((tid & 7) ^ (rr & 7)) * 8);   // pre-swizzled global column (elems)
    const char* Ag = (const char*)A + ((size_t)(row0 + rr) * K + cswz) * 2;
    const char* Bg = (const char*)WT + ((size_t)(col0 + rr) * K + cswz) * 2;

    f32x4 acc[2][4] = {};
    int ktiles = K >> 6;

    auto stage = [&](int buf, int k0) {
        const char* Agk = Ag + (size_t)k0 * 2;
        const char* Bgk = Bg + (size_t)k0 * 2;
        #pragma unroll
        for (int i = 0; i < 2; i++)
            load_lds_16(Agk + (size_t)i * 32 * K * 2,
                        (char*)As + buf * 8192 + i * 4096 + w * 1024);
        #pragma unroll
        for (int i = 0; i < 4; i++)
            load_lds_16(Bgk + (size_t)i * 32 * K * 2,
                        (char*)Bs + buf * 16384 + i * 4096 + w * 1024);
    };

    stage(0, 0);
    __syncthreads();
    int cur = 0;
    int rxor = (l15 & 7) << 4;                 // read-side XOR (bytes)
    for (int t = 0; t < ktiles; ++t) {
        if (t + 1 < ktiles) stage(cur ^ 1, (t + 1) * 64);
        const char* Asb = (const char*)As + cur * 8192;
        const char* Bsb = (const char*)Bs + cur * 16384;
        #pragma unroll
        for (int kk = 0; kk < 2; kk++) {
            bf16x8 a[2], b[4];
            #pragma unroll
            for (int i = 0; i < 2; i++)
                a[i] = *(const bf16x8*)(Asb +
                        (wr * 32 + i * 16 + l15) * 128 + ((kk * 64 + l4 * 16) ^ rxor));
            #pragma unroll
            for (int j = 0; j < 4; j++)
                b[j] = *(const bf16x8*)(Bsb +
                        (wc * 64 + j * 16 + l15) * 128 + ((kk * 64 + l4 * 16) ^ rxor));
            #pragma unroll
            for (int i = 0; i < 2; i++)
                #pragma unroll
                for (int j = 0; j < 4; j++)
                    acc[i][j] = __builtin_amdgcn_mfma_f32_16x16x32_bf16(
                        a[i], b[j], acc[i][j], 0, 0, 0);
        }
        __syncthreads();
        cur ^= 1;
    }

    int rbase = l4 * 4;
    #pragma unroll
    for (int i = 0; i < 2; i++) {
        #pragma unroll
        for (int j = 0; j < 4; j++) {
            int col = col0 + wc * 64 + j * 16 + l15;
            float bv = BIAS ? bias[col] : 0.0f;
            #pragma unroll
            for (int r = 0; r < 4; r++) {
                int row = row0 + wr * 32 + i * 16 + rbase + r;
                size_t off = (size_t)row * N + col;
                float v = acc[i][j][r] + bv;
                if (RES) v += res[off];
                if (RELU) v = fmaxf(v, 0.0f);
                if (OUTF) outF[off] = v;
                if (OUTB) outB[off] = __float2bfloat16(v);
            }
        }
    }
}

// ---------------- flash attention: QBLK=128, 8 waves x 16 q-rows --------------
// 1-D grid of 384 blocks x 512 threads. XCD-affinity: all 8 q-chunks of one
// (b,h) land on the same XCD (K/V stays in that XCD's L2); longest chunks
// dispatch first. 8 waves double resident waves/CU vs 4-wave QBLK=128 and
// halve per-thread staging + per-wave softmax work.
__global__ __launch_bounds__(512) void attn_flash_kernel(
    const __hip_bfloat16* __restrict__ qkvb,
    __hip_bfloat16* __restrict__ attb) {
    int tid = threadIdx.x;
    int lane = tid & 63;
    int w = tid >> 6;               // wave 0..7
    int l15 = lane & 15;
    int l4 = lane >> 4;

    int bid = blockIdx.x;            // 0..383
    int xcd = bid & 7, i = bid >> 3; // i 0..47
    int qc = 7 - (i / 6);            // descending: long blocks first
    int bh = (i % 6) * 8 + xcd;      // all qc of this bh share an XCD
    int b = bh / H_, h = bh % H_;
    int qb0 = qc * 128;

    __shared__ __align__(16) unsigned short Ks[64 * 64];      // swizzled [key][d]
    __shared__ __align__(16) unsigned short Vt[64 * 64];      // swizzled [d][key]
    __shared__ __align__(16) unsigned short Ps[8 * 16 * 64];  // per-wave [q][key]

    const unsigned short* qkv = (const unsigned short*)qkvb;
    const unsigned short* Qg = qkv + (size_t)(b * T_ + qb0) * QKV_ + h * HS_;
    const unsigned short* Kg = qkv + (size_t)b * T_ * QKV_ + C_ + h * HS_;
    const unsigned short* Vg = qkv + (size_t)b * T_ * QKV_ + 2 * C_ + h * HS_;

    // Q fragments: wave w owns q rows w*16 .. w*16+15
    bf16x8 qfrag[2];
    {
        const short* qrow = (const short*)Qg + (size_t)(w * 16 + l15) * QKV_;
        qfrag[0] = *(const bf16x8*)(qrow + l4 * 8);
        qfrag[1] = *(const bf16x8*)(qrow + 32 + l4 * 8);
    }

    f32x4 o_acc[4] = {};
    float m_run[4], l_run[4];
    #pragma unroll
    for (int r = 0; r < 4; r++) { m_run[r] = -1e30f; l_run[r] = 0.0f; }

    unsigned short* Pw = Ps + w * 16 * 64;
    int nkb = (qc + 1) * 2;

    for (int kbi = 0; kbi < nkb; ++kbi) {
        int k0 = kbi * 64;
        __syncthreads();
        // ---- stage K (swizzled) and V (transposed+swizzled), 512 threads ----
        {
            int key = tid >> 3, ch = tid & 7;   // key 0..63, ch 0..7
            u16x8 kv = *(const u16x8*)(Kg + (size_t)(k0 + key) * QKV_ + ch * 8);
            int byteoff = key * 128 + ((ch * 16) ^ ((key & 7) << 4));
            *(u16x8*)((char*)Ks + byteoff) = kv;

            u16x8 vv = *(const u16x8*)(Vg + (size_t)(k0 + key) * QKV_ + ch * 8);
            #pragma unroll
            for (int e = 0; e < 8; ++e) {
                int d = ch * 8 + e;
                int slot = (d ^ (d >> 3)) & 7;
                int boff = d * 128 + ((key * 2) ^ (slot << 4));
                *(unsigned short*)((char*)Vt + boff) = (unsigned short)vv[e];
            }
        }
        __syncthreads();

        // ---- S = Q K^T ----
        f32x4 s[4] = {};
        #pragma unroll
        for (int kk = 0; kk < 2; ++kk) {
            #pragma unroll
            for (int nt = 0; nt < 4; ++nt) {
                int key = nt * 16 + l15;
                int boff = key * 128 + (((l4 * 16) + kk * 64) ^ ((key & 7) << 4));
                bf16x8 kf = *(const bf16x8*)((char*)Ks + boff);
                s[nt] = __builtin_amdgcn_mfma_f32_16x16x32_bf16(qfrag[kk], kf, s[nt], 0, 0, 0);
            }
        }

        // ---- scale + causal mask (only the diagonal q-chunk's 2 tiles) ----
        bool maskt = (kbi >= 2 * qc);
        #pragma unroll
        for (int nt = 0; nt < 4; ++nt)
            #pragma unroll
            for (int r = 0; r < 4; ++r) {
                float v = s[nt][r] * 0.125f;
                if (maskt) {
                    int key = k0 + nt * 16 + l15;
                    int q = qb0 + w * 16 + l4 * 4 + r;
                    if (key > q) v = -1e30f;
                }
                s[nt][r] = v;
            }

        // ---- online softmax (per q-row, 16-lane group reduce) ----
        #pragma unroll
        for (int r = 0; r < 4; ++r) {
            float mx = fmaxf(fmaxf(s[0][r], s[1][r]), fmaxf(s[2][r], s[3][r]));
            #pragma unroll
            for (int o = 8; o; o >>= 1) mx = fmaxf(mx, __shfl_xor(mx, o));
            float mnew = fmaxf(m_run[r], mx);
            float alpha = __expf(m_run[r] - mnew);
            m_run[r] = mnew;
            float rs = 0.0f;
            #pragma unroll
            for (int nt = 0; nt < 4; ++nt) {
                float p = __expf(s[nt][r] - mnew);
                s[nt][r] = p;
                rs += p;
            }
            #pragma unroll
            for (int o = 8; o; o >>= 1) rs += __shfl_xor(rs, o);
            l_run[r] = l_run[r] * alpha + rs;
            #pragma unroll
            for (int nt = 0; nt < 4; ++nt) o_acc[nt][r] *= alpha;
        }

        // ---- write P to per-wave LDS (C layout -> swizzled [q][key]) ----
        #pragma unroll
        for (int nt = 0; nt < 4; ++nt)
            #pragma unroll
            for (int r = 0; r < 4; ++r) {
                int q = l4 * 4 + r;
                int col = nt * 16 + l15;
                int boff = q * 128 + ((col * 2) ^ ((q & 7) << 4));
                *(unsigned short*)((char*)Pw + boff) = f2bbits(s[nt][r]);
            }

        // ---- O += P V ----
        #pragma unroll
        for (int kk = 0; kk < 2; ++kk) {
            int q = l15;
            int pboff = q * 128 + (((l4 * 16) + kk * 64) ^ ((q & 7) << 4));
            bf16x8 pf = *(const bf16x8*)((char*)Pw + pboff);
            #pragma unroll
            for (int nt = 0; nt < 4; ++nt) {
                int d = nt * 16 + l15;
                int dslot = (d ^ (d >> 3)) & 7;
                int vboff = d * 128 + (((l4 * 16) + kk * 64) ^ (dslot << 4));
                bf16x8 vf = *(const bf16x8*)((char*)Vt + vboff);
                o_acc[nt] = __builtin_amdgcn_mfma_f32_16x16x32_bf16(pf, vf, o_acc[nt], 0, 0, 0);
            }
        }
    }

    // ---- epilogue ----
    unsigned short* Og = (unsigned short*)attb + (size_t)(b * T_ + qb0) * C_ + h * HS_;
    #pragma unroll
    for (int r = 0; r < 4; ++r) {
        float inv = 1.0f / l_run[r];
        #pragma unroll
        for (int nt = 0; nt < 4; ++nt) {
            float val = o_acc[nt][r] * inv;
            Og[(size_t)(w * 16 + l4 * 4 + r) * C_ + nt * 16 + l15] = f2bbits(val);
        }
    }
}

// ---------------- loss ----------------
__global__ void loss_rows_kernel(const float* __restrict__ logits,
                                 const int* __restrict__ targets,
                                 float* __restrict__ partials) {
    int row = blockIdx.x, tid = threadIdx.x;
    const float* lr = logits + (size_t)row * V_;
    __shared__ float red[256];
    float mx = -1e30f;
    for (int i = tid; i < V_; i += 256) mx = fmaxf(mx, lr[i]);
    red[tid] = mx;
    __syncthreads();
    for (int s = 128; s; s >>= 1) {
        if (tid < s) red[tid] = fmaxf(red[tid], red[tid + s]);
        __syncthreads();
    }
    mx = red[0];
    __syncthreads();
    float sum = 0.0f;
    for (int i = tid; i < V_; i += 256) sum += __expf(lr[i] - mx);
    red[tid] = sum;
    __syncthreads();
    for (int s = 128; s; s >>= 1) {
        if (tid < s) red[tid] += red[tid + s];
        __syncthreads();
    }
    if (tid == 0) {
        float lse = mx + __logf(red[0]);
        partials[row] = lse - lr[targets[row]];
    }
}

__global__ void loss_reduce_kernel(const float* __restrict__ partials,
                                   float* __restrict__ out) {
    int tid = threadIdx.x;
    float s = 0.0f;
    for (int i = tid; i < M_; i += 256) s += partials[i];
    __shared__ float red[256];
    red[tid] = s;
    __syncthreads();
    for (int st = 128; st; st >>= 1) {
        if (tid < st) red[tid] += red[tid + st];
        __syncthreads();
    }
    if (tid == 0) out[0] = red[0] * (1.0f / M_);
}

// ---------------- launch ----------------
extern "C" void kernel_launch(void* const* d_in, const int* in_sizes, int n_in,
                              void* d_out, int out_size, void* d_ws, size_t ws_size,
                              hipStream_t stream) {
    const int*   idx     = (const int*)d_in[0];
    const int*   targets = (const int*)d_in[1];
    const float* wte     = (const float*)d_in[2];
    const float* wpe     = (const float*)d_in[3];
    const float* lm_b    = (const float*)d_in[4];
    const float* ln1_w   = (const float*)d_in[5];
    const float* ln1_b   = (const float*)d_in[6];
    const float* Wq      = (const float*)d_in[7];
    const float* Wk      = (const float*)d_in[8];
    const float* Wv      = (const float*)d_in[9];
    const float* projW   = (const float*)d_in[10];
    const float* projb   = (const float*)d_in[11];
    const float* ln2_w   = (const float*)d_in[12];
    const float* ln2_b   = (const float*)d_in[13];
    const float* fc1W    = (const float*)d_in[14];
    const float* fc1b    = (const float*)d_in[15];
    const float* fc2W    = (const float*)d_in[16];
    const float* fc2b    = (const float*)d_in[17];
    const float* lnfw    = (const float*)d_in[18];
    const float* lnfb    = (const float*)d_in[19];

    char* ws = (char*)d_ws;
    size_t off = 0;
    float* x = (float*)(ws + off);                 off += (size_t)M_ * C_ * 4;
    __hip_bfloat16* h    = (__hip_bfloat16*)(ws + off); off += (size_t)M_ * C_ * 2;
    size_t qkv_off = off;
    __hip_bfloat16* qkvb = (__hip_bfloat16*)(ws + off); off += (size_t)M_ * QKV_ * 2;
    __hip_bfloat16* attb = (__hip_bfloat16*)(ws + off); off += (size_t)M_ * C_ * 2;
    __hip_bfloat16* fb   = (__hip_bfloat16*)(ws + qkv_off);  // aliases qkvb+attb
    __hip_bfloat16* wteB = (__hip_bfloat16*)(ws + off); off += (size_t)V_ * C_ * 2;
    float* partials = (float*)(ws + off);          off += (size_t)M_ * 4;

    const size_t QKV_SZ = (size_t)QKV_ * C_;
    const size_t WP_SZ  = (size_t)C_ * C_;
    const size_t F1_SZ  = (size_t)C_ * F_;
    const size_t F2_SZ  = (size_t)F_ * C_;
    size_t upfront_bytes = off + 2 * (size_t)L_ * (QKV_SZ + WP_SZ + F1_SZ + F2_SZ);
    bool upfront = ws_size >= upfront_bytes;
    int rep = upfront ? L_ : 1;

    __hip_bfloat16* qkvT0 = (__hip_bfloat16*)(ws + off); off += 2 * (size_t)rep * QKV_SZ;
    __hip_bfloat16* wpT0  = (__hip_bfloat16*)(ws + off); off += 2 * (size_t)rep * WP_SZ;
    __hip_bfloat16* wf1T0 = (__hip_bfloat16*)(ws + off); off += 2 * (size_t)rep * F1_SZ;
    __hip_bfloat16* wf2T0 = (__hip_bfloat16*)(ws + off); off += 2 * (size_t)rep * F2_SZ;

    float* logits = (float*)d_out;
    float* loss   = (float*)d_out + (size_t)M_ * V_;

    convert_bf16_kernel<<<(V_ * C_ + 255) / 256, 256, 0, stream>>>(wte, wteB, V_ * C_);
    embed_kernel<<<(M_ * C_) / 256, 256, 0, stream>>>(idx, wte, wpe, x);

    if (upfront) {
        transpose_qkv_kernel<<<dim3(C_ / 32, C_ / 32, 3 * L_), dim3(32, 8), 0, stream>>>(
            Wq, Wk, Wv, qkvT0);
        transpose_bf16_kernel<<<dim3(C_ / 32, C_ / 32, L_), dim3(32, 8), 0, stream>>>(
            projW, wpT0, C_, C_, WP_SZ, WP_SZ);
        transpose_bf16_kernel<<<dim3(F_ / 32, C_ / 32, L_), dim3(32, 8), 0, stream>>>(
            fc1W, wf1T0, C_, F_, F1_SZ, F1_SZ);
        transpose_bf16_kernel<<<dim3(C_ / 32, F_ / 32, L_), dim3(32, 8), 0, stream>>>(
            fc2W, wf2T0, F_, C_, F2_SZ, F2_SZ);
    }

    for (int l = 0; l < L_; l++) {
        __hip_bfloat16* qkvT = qkvT0 + (upfront ? (size_t)l * QKV_SZ : 0);
        __hip_bfloat16* wpT  = wpT0  + (upfront ? (size_t)l * WP_SZ : 0);
        __hip_bfloat16* wf1T = wf1T0 + (upfront ? (size_t)l * F1_SZ : 0);
        __hip_bfloat16* wf2T = wf2T0 + (upfront ? (size_t)l * F2_SZ : 0);

        ln_kernel<<<M_, 256, 0, stream>>>(x, ln1_w + l * C_, ln1_b + l * C_, h);

        if (!upfront)
            transpose_qkv_kernel<<<dim3(C_ / 32, C_ / 32, 3), dim3(32, 8), 0, stream>>>(
                Wq + (size_t)l * C_ * C_, Wk + (size_t)l * C_ * C_,
                Wv + (size_t)l * C_ * C_, qkvT);

        gemm64x128_kernel<false, false, false, false, true>
            <<<(M_ / 64) * (QKV_ / 128), 256, 0, stream>>>(
            h, qkvT, nullptr, nullptr, nullptr, qkvb, M_, QKV_, C_, QKV_ / 128);

        attn_flash_kernel<<<B_ * H_ * (T_ / 128), 512, 0, stream>>>(qkvb, attb);

        if (!upfront)
            transpose_bf16_kernel<<<dim3(C_ / 32, C_ / 32, 1), dim3(32, 8), 0, stream>>>(
                projW + (size_t)l * C_ * C_, wpT, C_, C_, 0, 0);
        gemm64x128_kernel<true, true, false, true, false>
            <<<(M_ / 64) * (C_ / 128), 256, 0, stream>>>(
            attb, wpT, projb + l * C_, x, x, nullptr, M_, C_, C_, C_ / 128);

        ln_kernel<<<M_, 256, 0, stream>>>(x, ln2_w + l * C_, ln2_b + l * C_, h);

        if (!upfront)
            transpose_bf16_kernel<<<dim3(F_ / 32, C_ / 32, 1), dim3(32, 8), 0, stream>>>(
                fc1W + (size_t)l * C_ * F_, wf1T, C_, F_, 0, 0);
        gemm64x128_kernel<true, false, true, false, true>
            <<<(M_ / 64) * (F_ / 128), 256, 0, stream>>>(
            h, wf1T, fc1b + l * F_, nullptr, nullptr, fb, M_, F_, C_, F_ / 128);

        if (!upfront)
            transpose_bf16_kernel<<<dim3(C_ / 32, F_ / 32, 1), dim3(32, 8), 0, stream>>>(
                fc2W + (size_t)l * F_ * C_, wf2T, F_, C_, 0, 0);
        gemm64x128_kernel<true, true, false, true, false>
            <<<(M_ / 64) * (C_ / 128), 256, 0, stream>>>(
            fb, wf2T, fc2b + l * C_, x, x, nullptr, M_, C_, F_, C_ / 128);
    }

    ln_kernel<<<M_, 256, 0, stream>>>(x, lnfw, lnfb, h);
    gemm64x128_kernel<true, false, false, true, false>
        <<<(M_ / 64) * (V_ / 128), 256, 0, stream>>>(
        h, wteB, lm_b, nullptr, logits, nullptr, M_, V_, C_, V_ / 128);

    loss_rows_kernel<<<M_, 256, 0, stream>>>(logits, targets, partials);
    loss_reduce_kernel<<<1, 256, 0, stream>>>(partials, loss);
}

// Round 8
// 1082.248 us; speedup vs baseline: 6.8080x; 1.0183x over previous
//
#include <hip/hip_runtime.h>
#include <hip/hip_bf16.h>

typedef short bf16x8 __attribute__((ext_vector_type(8)));
typedef unsigned short u16x8 __attribute__((ext_vector_type(8)));
typedef float f32x4 __attribute__((ext_vector_type(4)));

#define B_ 4
#define T_ 1024
#define V_ 1024
#define C_ 768
#define H_ 12
#define HS_ 64
#define L_ 6
#define F_ 3072
#define M_ (B_ * T_)   // 4096 rows
#define QKV_ 2304      // fused q|k|v width

__device__ inline float b2f(unsigned short u) {
    return __uint_as_float(((unsigned int)u) << 16);
}
__device__ inline unsigned short f2bbits(float f) {
    __hip_bfloat16 h = __float2bfloat16(f);
    return *(unsigned short*)&h;
}
__device__ inline void load_lds_16(const void* g, void* l) {
    __builtin_amdgcn_global_load_lds(
        (const __attribute__((address_space(1))) unsigned int*)g,
        (__attribute__((address_space(3))) unsigned int*)l, 16, 0, 0);
}

// ---------------- elementwise / embedding ----------------
__global__ void convert_bf16_kernel(const float* __restrict__ in,
                                    __hip_bfloat16* __restrict__ out, int n) {
    int i = blockIdx.x * 256 + threadIdx.x;
    if (i < n) out[i] = __float2bfloat16(in[i]);
}

__global__ void embed_kernel(const int* __restrict__ idx,
                             const float* __restrict__ wte,
                             const float* __restrict__ wpe,
                             float* __restrict__ x) {
    int i = blockIdx.x * 256 + threadIdx.x;  // 0 .. M_*C_-1
    int row = i / C_;
    int c = i - row * C_;
    int t = row & (T_ - 1);
    x[i] = wte[(size_t)idx[row] * C_ + c] + wpe[(size_t)t * C_ + c];
}

// ---------------- layernorm (row of 768, block 256) ----------------
__global__ void ln_kernel(const float* __restrict__ x,
                          const float* __restrict__ w,
                          const float* __restrict__ b,
                          __hip_bfloat16* __restrict__ out) {
    int row = blockIdx.x, tid = threadIdx.x;
    const float* xr = x + (size_t)row * C_;
    float v0 = xr[tid], v1 = xr[tid + 256], v2 = xr[tid + 512];
    __shared__ float red[256];
    red[tid] = v0 + v1 + v2;
    __syncthreads();
    for (int s = 128; s; s >>= 1) {
        if (tid < s) red[tid] += red[tid + s];
        __syncthreads();
    }
    float mean = red[0] * (1.0f / C_);
    __syncthreads();
    float d0 = v0 - mean, d1 = v1 - mean, d2 = v2 - mean;
    red[tid] = d0 * d0 + d1 * d1 + d2 * d2;
    __syncthreads();
    for (int s = 128; s; s >>= 1) {
        if (tid < s) red[tid] += red[tid + s];
        __syncthreads();
    }
    float rstd = rsqrtf(red[0] * (1.0f / C_) + 1e-5f);
    __hip_bfloat16* o = out + (size_t)row * C_;
    o[tid]       = __float2bfloat16(d0 * rstd * w[tid]       + b[tid]);
    o[tid + 256] = __float2bfloat16(d1 * rstd * w[tid + 256] + b[tid + 256]);
    o[tid + 512] = __float2bfloat16(d2 * rstd * w[tid + 512] + b[tid + 512]);
}

// ---------------- transpose-convert W[K][N] f32 -> WT[N][K] bf16 ----------------
__global__ void transpose_bf16_kernel(const float* __restrict__ W,
                                      __hip_bfloat16* __restrict__ WT,
                                      int K, int N,
                                      size_t sStride, size_t dStride) {
    int l = blockIdx.z;
    W += (size_t)l * sStride;
    WT += (size_t)l * dStride;
    __shared__ float tile[32][33];
    int n0 = blockIdx.x * 32, k0 = blockIdx.y * 32;
    int tx = threadIdx.x, ty = threadIdx.y;  // 32 x 8
    #pragma unroll
    for (int i = 0; i < 4; i++)
        tile[ty + 8 * i][tx] = W[(size_t)(k0 + ty + 8 * i) * N + n0 + tx];
    __syncthreads();
    #pragma unroll
    for (int i = 0; i < 4; i++)
        WT[(size_t)(n0 + ty + 8 * i) * K + k0 + tx] =
            __float2bfloat16(tile[tx][ty + 8 * i]);
}

// qkv: blockIdx.z = l*3 + which, dst packed [QKV][C] per layer
__global__ void transpose_qkv_kernel(const float* __restrict__ Wq,
                                     const float* __restrict__ Wk,
                                     const float* __restrict__ Wv,
                                     __hip_bfloat16* __restrict__ dst) {
    int z = blockIdx.z;
    int l = z / 3, which = z % 3;
    const float* W = (which == 0 ? Wq : which == 1 ? Wk : Wv) + (size_t)l * C_ * C_;
    __hip_bfloat16* WT = dst + (size_t)l * QKV_ * C_ + (size_t)which * C_ * C_;
    __shared__ float tile[32][33];
    int n0 = blockIdx.x * 32, k0 = blockIdx.y * 32;
    int tx = threadIdx.x, ty = threadIdx.y;
    #pragma unroll
    for (int i = 0; i < 4; i++)
        tile[ty + 8 * i][tx] = W[(size_t)(k0 + ty + 8 * i) * C_ + n0 + tx];
    __syncthreads();
    #pragma unroll
    for (int i = 0; i < 4; i++)
        WT[(size_t)(n0 + ty + 8 * i) * C_ + k0 + tx] =
            __float2bfloat16(tile[tx][ty + 8 * i]);
}

// ---------------- MFMA GEMM: 64x128 tile, BK=64, dbuf LDS -------------------
// T4 counted-vmcnt pipeline: stage(t+1) -> s_waitcnt vmcnt(6) (tile t landed,
// t+1's 6 loads stay in flight) -> barrier -> MFMA on tile t -> barrier
// (protects buffer reuse). Tile t's load latency hides under a full K-step.
template <bool BIAS, bool RES, bool RELU, bool OUTF, bool OUTB>
__global__ __launch_bounds__(256) void gemm64x128_kernel(
    const __hip_bfloat16* __restrict__ A,
    const __hip_bfloat16* __restrict__ WT,
    const float* __restrict__ bias,
    const float* __restrict__ res,
    float* __restrict__ outF,
    __hip_bfloat16* __restrict__ outB,
    int M, int N, int K, int nbx) {
    __shared__ __align__(16) short As[2 * 64 * 64];    // 2 x 8 KB
    __shared__ __align__(16) short Bs[2 * 128 * 64];   // 2 x 16 KB
    int tid = threadIdx.x;
    int lane = tid & 63;
    int w = tid >> 6;
    int l15 = lane & 15, l4 = lane >> 4;

    int nwg = gridDim.x;
    int bid = blockIdx.x;
    int sbid = (bid & 7) * (nwg >> 3) + (bid >> 3);
    int bx = sbid % nbx, by = sbid / nbx;
    int row0 = by * 64, col0 = bx * 128;

    int wr = w >> 1, wc = w & 1;

    int rr = tid >> 3;
    int cswz = (((tid & 7) ^ (rr & 7)) * 8);   // pre-swizzled global column (elems)
    const char* Ag = (const char*)A + ((size_t)(row0 + rr) * K + cswz) * 2;
    const char* Bg = (const char*)WT + ((size_t)(col0 + rr) * K + cswz) * 2;

    f32x4 acc[2][4] = {};
    int ktiles = K >> 6;

    auto stage = [&](int buf, int k0) {
        const char* Agk = Ag + (size_t)k0 * 2;
        const char* Bgk = Bg + (size_t)k0 * 2;
        #pragma unroll
        for (int i = 0; i < 2; i++)
            load_lds_16(Agk + (size_t)i * 32 * K * 2,
                        (char*)As + buf * 8192 + i * 4096 + w * 1024);
        #pragma unroll
        for (int i = 0; i < 4; i++)
            load_lds_16(Bgk + (size_t)i * 32 * K * 2,
                        (char*)Bs + buf * 16384 + i * 4096 + w * 1024);
    };

    stage(0, 0);                       // 6 loads in flight
    int cur = 0;
    int rxor = (l15 & 7) << 4;         // read-side XOR (bytes)
    for (int t = 0; t < ktiles; ++t) {
        if (t + 1 < ktiles) {
            stage(cur ^ 1, (t + 1) * 64);                    // +6 loads
            asm volatile("s_waitcnt vmcnt(6)" ::: "memory"); // tile t landed
        } else {
            asm volatile("s_waitcnt vmcnt(0)" ::: "memory");
        }
        __builtin_amdgcn_s_barrier();      // all waves' tile-t data in LDS
        asm volatile("" ::: "memory");
        const char* Asb = (const char*)As + cur * 8192;
        const char* Bsb = (const char*)Bs + cur * 16384;
        #pragma unroll
        for (int kk = 0; kk < 2; kk++) {
            bf16x8 a[2], b[4];
            #pragma unroll
            for (int i = 0; i < 2; i++)
                a[i] = *(const bf16x8*)(Asb +
                        (wr * 32 + i * 16 + l15) * 128 + ((kk * 64 + l4 * 16) ^ rxor));
            #pragma unroll
            for (int j = 0; j < 4; j++)
                b[j] = *(const bf16x8*)(Bsb +
                        (wc * 64 + j * 16 + l15) * 128 + ((kk * 64 + l4 * 16) ^ rxor));
            #pragma unroll
            for (int i = 0; i < 2; i++)
                #pragma unroll
                for (int j = 0; j < 4; j++)
                    acc[i][j] = __builtin_amdgcn_mfma_f32_16x16x32_bf16(
                        a[i], b[j], acc[i][j], 0, 0, 0);
        }
        asm volatile("" ::: "memory");
        __builtin_amdgcn_s_barrier();      // buf cur free for overwrite next iter
        cur ^= 1;
    }

    int rbase = l4 * 4;
    #pragma unroll
    for (int i = 0; i < 2; i++) {
        #pragma unroll
        for (int j = 0; j < 4; j++) {
            int col = col0 + wc * 64 + j * 16 + l15;
            float bv = BIAS ? bias[col] : 0.0f;
            #pragma unroll
            for (int r = 0; r < 4; r++) {
                int row = row0 + wr * 32 + i * 16 + rbase + r;
                size_t off = (size_t)row * N + col;
                float v = acc[i][j][r] + bv;
                if (RES) v += res[off];
                if (RELU) v = fmaxf(v, 0.0f);
                if (OUTF) outF[off] = v;
                if (OUTB) outB[off] = __float2bfloat16(v);
            }
        }
    }
}

// ---------------- flash attention: QBLK=128, 8 waves x 16 q-rows --------------
__global__ __launch_bounds__(512) void attn_flash_kernel(
    const __hip_bfloat16* __restrict__ qkvb,
    __hip_bfloat16* __restrict__ attb) {
    int tid = threadIdx.x;
    int lane = tid & 63;
    int w = tid >> 6;               // wave 0..7
    int l15 = lane & 15;
    int l4 = lane >> 4;

    int bid = blockIdx.x;            // 0..383
    int xcd = bid & 7, i = bid >> 3; // i 0..47
    int qc = 7 - (i / 6);            // descending: long blocks first
    int bh = (i % 6) * 8 + xcd;      // all qc of this bh share an XCD
    int b = bh / H_, h = bh % H_;
    int qb0 = qc * 128;

    __shared__ __align__(16) unsigned short Ks[64 * 64];      // swizzled [key][d]
    __shared__ __align__(16) unsigned short Vt[64 * 64];      // swizzled [d][key]
    __shared__ __align__(16) unsigned short Ps[8 * 16 * 64];  // per-wave [q][key]

    const unsigned short* qkv = (const unsigned short*)qkvb;
    const unsigned short* Qg = qkv + (size_t)(b * T_ + qb0) * QKV_ + h * HS_;
    const unsigned short* Kg = qkv + (size_t)b * T_ * QKV_ + C_ + h * HS_;
    const unsigned short* Vg = qkv + (size_t)b * T_ * QKV_ + 2 * C_ + h * HS_;

    // Q fragments: wave w owns q rows w*16 .. w*16+15
    bf16x8 qfrag[2];
    {
        const short* qrow = (const short*)Qg + (size_t)(w * 16 + l15) * QKV_;
        qfrag[0] = *(const bf16x8*)(qrow + l4 * 8);
        qfrag[1] = *(const bf16x8*)(qrow + 32 + l4 * 8);
    }

    f32x4 o_acc[4] = {};
    float m_run[4], l_run[4];
    #pragma unroll
    for (int r = 0; r < 4; r++) { m_run[r] = -1e30f; l_run[r] = 0.0f; }

    unsigned short* Pw = Ps + w * 16 * 64;
    int nkb = (qc + 1) * 2;

    for (int kbi = 0; kbi < nkb; ++kbi) {
        int k0 = kbi * 64;
        __syncthreads();
        // ---- stage K (swizzled) and V (transposed+swizzled), 512 threads ----
        {
            int key = tid >> 3, ch = tid & 7;   // key 0..63, ch 0..7
            u16x8 kv = *(const u16x8*)(Kg + (size_t)(k0 + key) * QKV_ + ch * 8);
            int byteoff = key * 128 + ((ch * 16) ^ ((key & 7) << 4));
            *(u16x8*)((char*)Ks + byteoff) = kv;

            u16x8 vv = *(const u16x8*)(Vg + (size_t)(k0 + key) * QKV_ + ch * 8);
            #pragma unroll
            for (int e = 0; e < 8; ++e) {
                int d = ch * 8 + e;
                int slot = (d ^ (d >> 3)) & 7;
                int boff = d * 128 + ((key * 2) ^ (slot << 4));
                *(unsigned short*)((char*)Vt + boff) = (unsigned short)vv[e];
            }
        }
        __syncthreads();

        // ---- S = Q K^T ----
        f32x4 s[4] = {};
        #pragma unroll
        for (int kk = 0; kk < 2; ++kk) {
            #pragma unroll
            for (int nt = 0; nt < 4; ++nt) {
                int key = nt * 16 + l15;
                int boff = key * 128 + (((l4 * 16) + kk * 64) ^ ((key & 7) << 4));
                bf16x8 kf = *(const bf16x8*)((char*)Ks + boff);
                s[nt] = __builtin_amdgcn_mfma_f32_16x16x32_bf16(qfrag[kk], kf, s[nt], 0, 0, 0);
            }
        }

        // ---- scale + causal mask (only the diagonal q-chunk's 2 tiles) ----
        bool maskt = (kbi >= 2 * qc);
        #pragma unroll
        for (int nt = 0; nt < 4; ++nt)
            #pragma unroll
            for (int r = 0; r < 4; ++r) {
                float v = s[nt][r] * 0.125f;
                if (maskt) {
                    int key = k0 + nt * 16 + l15;
                    int q = qb0 + w * 16 + l4 * 4 + r;
                    if (key > q) v = -1e30f;
                }
                s[nt][r] = v;
            }

        // ---- online softmax (per q-row, 16-lane group reduce) ----
        #pragma unroll
        for (int r = 0; r < 4; ++r) {
            float mx = fmaxf(fmaxf(s[0][r], s[1][r]), fmaxf(s[2][r], s[3][r]));
            #pragma unroll
            for (int o = 8; o; o >>= 1) mx = fmaxf(mx, __shfl_xor(mx, o));
            float mnew = fmaxf(m_run[r], mx);
            float alpha = __expf(m_run[r] - mnew);
            m_run[r] = mnew;
            float rs = 0.0f;
            #pragma unroll
            for (int nt = 0; nt < 4; ++nt) {
                float p = __expf(s[nt][r] - mnew);
                s[nt][r] = p;
                rs += p;
            }
            #pragma unroll
            for (int o = 8; o; o >>= 1) rs += __shfl_xor(rs, o);
            l_run[r] = l_run[r] * alpha + rs;
            #pragma unroll
            for (int nt = 0; nt < 4; ++nt) o_acc[nt][r] *= alpha;
        }

        // ---- write P to per-wave LDS (C layout -> swizzled [q][key]) ----
        #pragma unroll
        for (int nt = 0; nt < 4; ++nt)
            #pragma unroll
            for (int r = 0; r < 4; ++r) {
                int q = l4 * 4 + r;
                int col = nt * 16 + l15;
                int boff = q * 128 + ((col * 2) ^ ((q & 7) << 4));
                *(unsigned short*)((char*)Pw + boff) = f2bbits(s[nt][r]);
            }

        // ---- O += P V ----
        #pragma unroll
        for (int kk = 0; kk < 2; ++kk) {
            int q = l15;
            int pboff = q * 128 + (((l4 * 16) + kk * 64) ^ ((q & 7) << 4));
            bf16x8 pf = *(const bf16x8*)((char*)Pw + pboff);
            #pragma unroll
            for (int nt = 0; nt < 4; ++nt) {
                int d = nt * 16 + l15;
                int dslot = (d ^ (d >> 3)) & 7;
                int vboff = d * 128 + (((l4 * 16) + kk * 64) ^ (dslot << 4));
                bf16x8 vf = *(const bf16x8*)((char*)Vt + vboff);
                o_acc[nt] = __builtin_amdgcn_mfma_f32_16x16x32_bf16(pf, vf, o_acc[nt], 0, 0, 0);
            }
        }
    }

    // ---- epilogue ----
    unsigned short* Og = (unsigned short*)attb + (size_t)(b * T_ + qb0) * C_ + h * HS_;
    #pragma unroll
    for (int r = 0; r < 4; ++r) {
        float inv = 1.0f / l_run[r];
        #pragma unroll
        for (int nt = 0; nt < 4; ++nt) {
            float val = o_acc[nt][r] * inv;
            Og[(size_t)(w * 16 + l4 * 4 + r) * C_ + nt * 16 + l15] = f2bbits(val);
        }
    }
}

// ---------------- loss ----------------
__global__ void loss_rows_kernel(const float* __restrict__ logits,
                                 const int* __restrict__ targets,
                                 float* __restrict__ partials) {
    int row = blockIdx.x, tid = threadIdx.x;
    const float* lr = logits + (size_t)row * V_;
    __shared__ float red[256];
    float mx = -1e30f;
    for (int i = tid; i < V_; i += 256) mx = fmaxf(mx, lr[i]);
    red[tid] = mx;
    __syncthreads();
    for (int s = 128; s; s >>= 1) {
        if (tid < s) red[tid] = fmaxf(red[tid], red[tid + s]);
        __syncthreads();
    }
    mx = red[0];
    __syncthreads();
    float sum = 0.0f;
    for (int i = tid; i < V_; i += 256) sum += __expf(lr[i] - mx);
    red[tid] = sum;
    __syncthreads();
    for (int s = 128; s; s >>= 1) {
        if (tid < s) red[tid] += red[tid + s];
        __syncthreads();
    }
    if (tid == 0) {
        float lse = mx + __logf(red[0]);
        partials[row] = lse - lr[targets[row]];
    }
}

__global__ void loss_reduce_kernel(const float* __restrict__ partials,
                                   float* __restrict__ out) {
    int tid = threadIdx.x;
    float s = 0.0f;
    for (int i = tid; i < M_; i += 256) s += partials[i];
    __shared__ float red[256];
    red[tid] = s;
    __syncthreads();
    for (int st = 128; st; st >>= 1) {
        if (tid < st) red[tid] += red[tid + st];
        __syncthreads();
    }
    if (tid == 0) out[0] = red[0] * (1.0f / M_);
}

// ---------------- launch ----------------
extern "C" void kernel_launch(void* const* d_in, const int* in_sizes, int n_in,
                              void* d_out, int out_size, void* d_ws, size_t ws_size,
                              hipStream_t stream) {
    const int*   idx     = (const int*)d_in[0];
    const int*   targets = (const int*)d_in[1];
    const float* wte     = (const float*)d_in[2];
    const float* wpe     = (const float*)d_in[3];
    const float* lm_b    = (const float*)d_in[4];
    const float* ln1_w   = (const float*)d_in[5];
    const float* ln1_b   = (const float*)d_in[6];
    const float* Wq      = (const float*)d_in[7];
    const float* Wk      = (const float*)d_in[8];
    const float* Wv      = (const float*)d_in[9];
    const float* projW   = (const float*)d_in[10];
    const float* projb   = (const float*)d_in[11];
    const float* ln2_w   = (const float*)d_in[12];
    const float* ln2_b   = (const float*)d_in[13];
    const float* fc1W    = (const float*)d_in[14];
    const float* fc1b    = (const float*)d_in[15];
    const float* fc2W    = (const float*)d_in[16];
    const float* fc2b    = (const float*)d_in[17];
    const float* lnfw    = (const float*)d_in[18];
    const float* lnfb    = (const float*)d_in[19];

    char* ws = (char*)d_ws;
    size_t off = 0;
    float* x = (float*)(ws + off);                 off += (size_t)M_ * C_ * 4;
    __hip_bfloat16* h    = (__hip_bfloat16*)(ws + off); off += (size_t)M_ * C_ * 2;
    size_t qkv_off = off;
    __hip_bfloat16* qkvb = (__hip_bfloat16*)(ws + off); off += (size_t)M_ * QKV_ * 2;
    __hip_bfloat16* attb = (__hip_bfloat16*)(ws + off); off += (size_t)M_ * C_ * 2;
    __hip_bfloat16* fb   = (__hip_bfloat16*)(ws + qkv_off);  // aliases qkvb+attb
    __hip_bfloat16* wteB = (__hip_bfloat16*)(ws + off); off += (size_t)V_ * C_ * 2;
    float* partials = (float*)(ws + off);          off += (size_t)M_ * 4;

    const size_t QKV_SZ = (size_t)QKV_ * C_;
    const size_t WP_SZ  = (size_t)C_ * C_;
    const size_t F1_SZ  = (size_t)C_ * F_;
    const size_t F2_SZ  = (size_t)F_ * C_;
    size_t upfront_bytes = off + 2 * (size_t)L_ * (QKV_SZ + WP_SZ + F1_SZ + F2_SZ);
    bool upfront = ws_size >= upfront_bytes;
    int rep = upfront ? L_ : 1;

    __hip_bfloat16* qkvT0 = (__hip_bfloat16*)(ws + off); off += 2 * (size_t)rep * QKV_SZ;
    __hip_bfloat16* wpT0  = (__hip_bfloat16*)(ws + off); off += 2 * (size_t)rep * WP_SZ;
    __hip_bfloat16* wf1T0 = (__hip_bfloat16*)(ws + off); off += 2 * (size_t)rep * F1_SZ;
    __hip_bfloat16* wf2T0 = (__hip_bfloat16*)(ws + off); off += 2 * (size_t)rep * F2_SZ;

    float* logits = (float*)d_out;
    float* loss   = (float*)d_out + (size_t)M_ * V_;

    convert_bf16_kernel<<<(V_ * C_ + 255) / 256, 256, 0, stream>>>(wte, wteB, V_ * C_);
    embed_kernel<<<(M_ * C_) / 256, 256, 0, stream>>>(idx, wte, wpe, x);

    if (upfront) {
        transpose_qkv_kernel<<<dim3(C_ / 32, C_ / 32, 3 * L_), dim3(32, 8), 0, stream>>>(
            Wq, Wk, Wv, qkvT0);
        transpose_bf16_kernel<<<dim3(C_ / 32, C_ / 32, L_), dim3(32, 8), 0, stream>>>(
            projW, wpT0, C_, C_, WP_SZ, WP_SZ);
        transpose_bf16_kernel<<<dim3(F_ / 32, C_ / 32, L_), dim3(32, 8), 0, stream>>>(
            fc1W, wf1T0, C_, F_, F1_SZ, F1_SZ);
        transpose_bf16_kernel<<<dim3(C_ / 32, F_ / 32, L_), dim3(32, 8), 0, stream>>>(
            fc2W, wf2T0, F_, C_, F2_SZ, F2_SZ);
    }

    for (int l = 0; l < L_; l++) {
        __hip_bfloat16* qkvT = qkvT0 + (upfront ? (size_t)l * QKV_SZ : 0);
        __hip_bfloat16* wpT  = wpT0  + (upfront ? (size_t)l * WP_SZ : 0);
        __hip_bfloat16* wf1T = wf1T0 + (upfront ? (size_t)l * F1_SZ : 0);
        __hip_bfloat16* wf2T = wf2T0 + (upfront ? (size_t)l * F2_SZ : 0);

        ln_kernel<<<M_, 256, 0, stream>>>(x, ln1_w + l * C_, ln1_b + l * C_, h);

        if (!upfront)
            transpose_qkv_kernel<<<dim3(C_ / 32, C_ / 32, 3), dim3(32, 8), 0, stream>>>(
                Wq + (size_t)l * C_ * C_, Wk + (size_t)l * C_ * C_,
                Wv + (size_t)l * C_ * C_, qkvT);

        gemm64x128_kernel<false, false, false, false, true>
            <<<(M_ / 64) * (QKV_ / 128), 256, 0, stream>>>(
            h, qkvT, nullptr, nullptr, nullptr, qkvb, M_, QKV_, C_, QKV_ / 128);

        attn_flash_kernel<<<B_ * H_ * (T_ / 128), 512, 0, stream>>>(qkvb, attb);

        if (!upfront)
            transpose_bf16_kernel<<<dim3(C_ / 32, C_ / 32, 1), dim3(32, 8), 0, stream>>>(
                projW + (size_t)l * C_ * C_, wpT, C_, C_, 0, 0);
        gemm64x128_kernel<true, true, false, true, false>
            <<<(M_ / 64) * (C_ / 128), 256, 0, stream>>>(
            attb, wpT, projb + l * C_, x, x, nullptr, M_, C_, C_, C_ / 128);

        ln_kernel<<<M_, 256, 0, stream>>>(x, ln2_w + l * C_, ln2_b + l * C_, h);

        if (!upfront)
            transpose_bf16_kernel<<<dim3(F_ / 32, C_ / 32, 1), dim3(32, 8), 0, stream>>>(
                fc1W + (size_t)l * C_ * F_, wf1T, C_, F_, 0, 0);
        gemm64x128_kernel<true, false, true, false, true>
            <<<(M_ / 64) * (F_ / 128), 256, 0, stream>>>(
            h, wf1T, fc1b + l * F_, nullptr, nullptr, fb, M_, F_, C_, F_ / 128);

        if (!upfront)
            transpose_bf16_kernel<<<dim3(C_ / 32, F_ / 32, 1), dim3(32, 8), 0, stream>>>(
                fc2W + (size_t)l * F_ * C_, wf2T, F_, C_, 0, 0);
        gemm64x128_kernel<true, true, false, true, false>
            <<<(M_ / 64) * (C_ / 128), 256, 0, stream>>>(
            fb, wf2T, fc2b + l * C_, x, x, nullptr, M_, C_, F_, C_ / 128);
    }

    ln_kernel<<<M_, 256, 0, stream>>>(x, lnfw, lnfb, h);
    gemm64x128_kernel<true, false, false, true, false>
        <<<(M_ / 64) * (V_ / 128), 256, 0, stream>>>(
        h, wteB, lm_b, nullptr, logits, nullptr, M_, V_, C_, V_ / 128);

    loss_rows_kernel<<<M_, 256, 0, stream>>>(logits, targets, partials);
    loss_reduce_kernel<<<1, 256, 0, stream>>>(partials, loss);
}